// Round 11
// baseline (260.292 us; speedup 1.0000x reference)
//
#include <hip/hip_runtime.h>
#include <hip/hip_bf16.h>
#include <math.h>
#include <float.h>

// x: [4,128,256,256] f32; conv_w: [4,128,128]; conv_g/b: [4,128]
// final_w: [128,640]; final_g/b: [128]; out: [4,128,256,256] f32
#define B_ 4
#define C_ 128
#define P_ 65536

// ---- workspace float offsets ----
#define M3_OFF      0        // [512][64] block maxima (32x32), exact fp32
#define M2_OFF      32768    // [512][16]
#define M1_OFF      40960    // [512][4]
#define M0_OFF      43008    // [512]
#define YBASE_      43520    // y levels, same internal layout as M
#define SCALED_OFF  87040    // [4][128]
#define SHIFTD_OFF  87552    // [4][128]
#define CONTRIB_OFF 88064    // [4][128][64]
#define S3_OFF      120832   // [512][64] block sums (32x32), exact fp32
#define SX_OFF      153600   // [512] per-(b,c) total sum
#define G_OFF       154112   // [4][128][128] Gram (bf16-sourced, fp32 accum)
#define SCALEF_OFF  219648   // [128]
#define SHIFTF_OFF  219776   // [128]
#define MAXP_OFF    219904   // [512 bc][64 blk][16 rr] fp32 max partials
#define SUMP_OFF    744192   // [512 bc][64 blk][16 rr] fp32 sum partials
// total floats: 1268480 (~4.84 MB)

using short8 = __attribute__((ext_vector_type(8))) short;
using f32x4 = __attribute__((ext_vector_type(4))) float;
using f32x16 = __attribute__((ext_vector_type(16))) float;

__device__ __forceinline__ int level_rel(int d) {
    return YBASE_ - 512 * (((1 << (2 * (d + 1))) - 1) / 3);
}

// RNE pack of two f32 into bf16x2 (low = first arg) — hardware v_cvt_pk_bf16_f32
__device__ __forceinline__ unsigned int bfpair(float a, float b) {
    union { __hip_bfloat162 h2; unsigned int u; } cv;
    cv.h2 = __float22bfloat162_rn(make_float2(a, b));
    return cv.u;
}

// K1: fused pass over x. Double-buffered [128 c][128 px] bf16 LDS tile,
// register-staged (T14 async-split): per phase each wave (a) issues next-tile
// global float4 loads early, (b) computes Gram MFMAs from the current bf16
// tile (1 ds_read_b128 per fragment), (c) waits the loads late, folds exact
// fp32 max/sum (BEFORE rounding), converts once via v_cvt_pk and ds_writes
// the other buffer, (d) one barrier. 4 phases, 5 barriers total.
// Wave w computes G-quadrants (w&3, 2*(w>>2)+{0,1}) via 32x32x16 MFMA.
// grid = 512 (b*128 + rc; rc covers image rows 2rc, 2rc+1), block 512.
__global__ __launch_bounds__(512, 4) void k_gram_pool(const float* __restrict__ x,
                                                      float* __restrict__ ws,
                                                      float* __restrict__ gpart) {
    __shared__ __align__(16) unsigned short buf[2][16384];  // 2 x [128 c][128 px] bf16, 32 KB each
    int wg = blockIdx.x;
    int b = wg >> 7, rc = wg & 127;
    const float* xb = x + (size_t)b * C_ * P_ + (size_t)rc * 512;
    int t_ = threadIdx.x, l = t_ & 63, wv = t_ >> 6;
    int qi = wv & 3;            // A quadrant-row
    int qjb = (wv >> 2) * 2;    // B quadrant-col base (2 quadrants per wave)
    int srow = wv * 16 + (l >> 2);  // staging channel row (0..127)
    int sq = l & 3;                 // staging 32-px quarter within the tile
    const float* sp = xb + (size_t)srow * P_ + sq * 32;

    f32x16 acc[2];
#pragma unroll
    for (int j = 0; j < 2; ++j)
#pragma unroll
        for (int r = 0; r < 16; ++r) acc[j][r] = 0.f;
    float mxcb[2] = {-FLT_MAX, -FLT_MAX};  // colblk cells sq and 4+sq (parities merged)
    float smcb[2] = {0.f, 0.f};
    float4 ld[8];

    // ---- staging helpers (ph is compile-time under full unroll) ----
#define SLOAD(ph)                                                            \
    do {                                                                     \
        _Pragma("unroll") for (int k_ = 0; k_ < 8; ++k_)                     \
            ld[k_] = *(const float4*)(sp + (ph) * 128 + k_ * 4);             \
    } while (0)
#define SSTORE(ph)                                                           \
    do {                                                                     \
        _Pragma("unroll") for (int k_ = 0; k_ < 8; ++k_) {                   \
            float4 v_ = ld[k_];                                              \
            mxcb[(ph) & 1] = fmaxf(mxcb[(ph) & 1],                           \
                fmaxf(fmaxf(v_.x, v_.y), fmaxf(v_.z, v_.w)));                \
            smcb[(ph) & 1] += (v_.x + v_.y) + (v_.z + v_.w);                 \
        }                                                                    \
        _Pragma("unroll") for (int k_ = 0; k_ < 4; ++k_) {                   \
            uint4 u_ = make_uint4(                                           \
                bfpair(ld[2 * k_].x, ld[2 * k_].y),                          \
                bfpair(ld[2 * k_].z, ld[2 * k_].w),                          \
                bfpair(ld[2 * k_ + 1].x, ld[2 * k_ + 1].y),                  \
                bfpair(ld[2 * k_ + 1].z, ld[2 * k_ + 1].w));                 \
            int ch_ = (sq * 4 + k_) ^ (srow & 7);                            \
            *(uint4*)(&buf[(ph) & 1][srow * 128 + ch_ * 8]) = u_;            \
        }                                                                    \
    } while (0)

    // prologue: tile 0
    SLOAD(0);
    SSTORE(0);
    __syncthreads();

#pragma unroll
    for (int ph = 0; ph < 4; ++ph) {
        if (ph < 3) SLOAD(ph + 1);  // issue early; latency hides under compute
        const unsigned short* tl = buf[ph & 1];
#pragma unroll
        for (int ks = 0; ks < 8; ++ks) {
            int ch = ks * 2 + (l >> 5);
            int rowa = qi * 32 + (l & 31);
            short8 fa = *(const short8*)(tl + rowa * 128 + ((ch ^ (rowa & 7)) * 8));
#pragma unroll
            for (int j = 0; j < 2; ++j) {
                int rowb = (qjb + j) * 32 + (l & 31);
                short8 fb = *(const short8*)(tl + rowb * 128 + ((ch ^ (rowb & 7)) * 8));
                acc[j] = __builtin_amdgcn_mfma_f32_32x32x16_bf16(fa, fb, acc[j], 0, 0, 0);
            }
        }
        if (ph < 3) SSTORE(ph + 1);  // vmcnt waits land here (late)
        __syncthreads();
    }
#undef SLOAD
#undef SSTORE

    // ---- write Gram partials [wg][128][128] (G symmetric -> layout-safe) ----
    size_t gb = (size_t)wg * 16384;
#pragma unroll
    for (int j = 0; j < 2; ++j)
#pragma unroll
        for (int r = 0; r < 16; ++r) {
            int row = qi * 32 + (r & 3) + 8 * (r >> 2) + 4 * (l >> 5);
            int col = (qjb + j) * 32 + (l & 31);
            gpart[gb + (size_t)row * 128 + col] = acc[j][r];
        }
    // ---- max/sum partials: per-lane cells (c=srow, colblk sq & 4+sq) ----
    {
        int i3 = rc >> 4, rr = rc & 15;
#pragma unroll
        for (int h = 0; h < 2; ++h) {
            int cb = h * 4 + sq;
            size_t idx = ((size_t)(b * 128 + srow) * 64 + i3 * 8 + cb) * 16 + rr;
            ws[MAXP_OFF + idx] = mxcb[h];
            ws[SUMP_OFF + idx] = smcb[h];
        }
    }
}

// K2a: reduce Gram partials over 128 row-chunks per b. grid = 256, block 256
__global__ __launch_bounds__(256) void k_reduceG(const float* __restrict__ gpart,
                                                 float* __restrict__ ws) {
    int tid = blockIdx.x * 256 + threadIdx.x;  // 65536
    int b = tid >> 14, inner = tid & 16383;
    const float* p = gpart + (size_t)b * 128 * 16384 + inner;
    float s = 0.f;
    for (int r = 0; r < 128; ++r) s += p[(size_t)r * 16384];
    ws[G_OFF + tid] = s;
}

// K2b: reduce max/sum partials -> M3/S3/SX + pyramid. grid = 512 (bc), block 256.
__global__ __launch_bounds__(256) void k_reduceMS(float* __restrict__ ws) {
    int bc = blockIdx.x;  // 512
    int t = threadIdx.x;
    int blk = t >> 2, q = t & 3;
    __shared__ float bm[64], bs[64];
    __shared__ float lv[24];
    __shared__ float sxr[8];
    {
        size_t base = (size_t)bc * 1024 + blk * 16 + q * 4;
        float4 mv = *(const float4*)(ws + MAXP_OFF + base);
        float4 sv = *(const float4*)(ws + SUMP_OFF + base);
        float m = fmaxf(fmaxf(mv.x, mv.y), fmaxf(mv.z, mv.w));
        float s = (sv.x + sv.y) + (sv.z + sv.w);
        m = fmaxf(m, __shfl_xor(m, 1)); s += __shfl_xor(s, 1);
        m = fmaxf(m, __shfl_xor(m, 2)); s += __shfl_xor(s, 2);
        if (q == 0) {
            bm[blk] = m;
            bs[blk] = s;
            ws[M3_OFF + (size_t)bc * 64 + blk] = m;
            ws[S3_OFF + (size_t)bc * 64 + blk] = s;
        }
    }
    __syncthreads();
    if (t < 8) {
        float sx = 0.f;
        for (int r = 0; r < 8; ++r) sx += bs[t * 8 + r];
        sxr[t] = sx;
    }
    if (t < 16) {
        int i2 = t >> 2, j2 = t & 3;
        float m = -FLT_MAX;
        for (int a = 0; a < 2; ++a)
            for (int b2 = 0; b2 < 2; ++b2)
                m = fmaxf(m, bm[(2 * i2 + a) * 8 + 2 * j2 + b2]);
        lv[t] = m;
        ws[M2_OFF + (size_t)bc * 16 + t] = m;
    }
    __syncthreads();
    if (t == 0) {
        float sx = 0.f;
        for (int r = 0; r < 8; ++r) sx += sxr[r];
        ws[SX_OFF + bc] = sx;
    }
    if (t < 4) {
        int i1 = t >> 1, j1 = t & 1;
        float m = -FLT_MAX;
        for (int a = 0; a < 2; ++a)
            for (int b2 = 0; b2 < 2; ++b2)
                m = fmaxf(m, lv[(2 * i1 + a) * 4 + 2 * j1 + b2]);
        lv[16 + t] = m;
        ws[M1_OFF + (size_t)bc * 4 + t] = m;
    }
    __syncthreads();
    if (t == 0)
        ws[M0_OFF + bc] = fmaxf(fmaxf(lv[16], lv[17]), fmaxf(lv[18], lv[19]));
}

// K3a: y_d[b,co,blk] = sum_ci M_d[b,ci,blk] * conv_w[d][co][ci]
__global__ __launch_bounds__(256) void k_conv_pool(const float* __restrict__ conv_w,
                                                   float* __restrict__ ws) {
    int bid = blockIdx.x;
    int d = bid >> 4, b = (bid >> 2) & 3, cchunk = bid & 3;
    int NB = 1 << (2 * d);
    int rel = level_rel(d);
    const float* Mb = ws + rel + (size_t)b * 128 * NB;
    float* Yb = ws + YBASE_ + rel + (size_t)b * 128 * NB;
    __shared__ float mlds[8192];
    int t = threadIdx.x;
    int tot = 128 * NB;
    for (int i = t; i < tot; i += 256) mlds[i] = Mb[i];
    __syncthreads();
    if (NB >= 4) {
        int nbq = NB >> 2;
        int nq = 32 * nbq;
        for (int qi = t; qi < nq; qi += 256) {
            int co = cchunk * 32 + (qi >> (2 * d - 2));
            int bq = qi & (nbq - 1);
            const float* wrow = conv_w + ((size_t)d * 128 + co) * 128;
            float a0 = 0.f, a1 = 0.f, a2 = 0.f, a3 = 0.f;
            for (int ci = 0; ci < 128; ++ci) {
                float4 mv = *(const float4*)(&mlds[ci * NB + bq * 4]);
                float wvv = wrow[ci];
                a0 = fmaf(wvv, mv.x, a0);
                a1 = fmaf(wvv, mv.y, a1);
                a2 = fmaf(wvv, mv.z, a2);
                a3 = fmaf(wvv, mv.w, a3);
            }
            float4 r;
            r.x = a0; r.y = a1; r.z = a2; r.w = a3;
            *(float4*)(&Yb[co * NB + bq * 4]) = r;
        }
    } else {
        for (int oi = t; oi < 32; oi += 256) {
            int co = cchunk * 32 + oi;
            const float* wrow = conv_w + (size_t)co * 128;
            float acc = 0.f;
            for (int ci = 0; ci < 128; ++ci) acc = fmaf(mlds[ci], wrow[ci], acc);
            Yb[co] = acc;
        }
    }
}

// K3b: per-(d,c) BN stats
__global__ __launch_bounds__(256) void k_bnstats_d(const float* __restrict__ conv_g,
                                                   const float* __restrict__ conv_b,
                                                   float* __restrict__ ws) {
    int tid = blockIdx.x * 256 + threadIdx.x;
    if (tid >= 512) return;
    int d = tid >> 7, c = tid & 127;
    int NB = 1 << (2 * d);
    const float* Y = ws + YBASE_ + level_rel(d);
    int n = 4 * NB;
    float s = 0.f;
    for (int b = 0; b < 4; ++b)
        for (int k = 0; k < NB; ++k) s += Y[((size_t)b * 128 + c) * NB + k];
    float mean = s / (float)n;
    float v = 0.f;
    for (int b = 0; b < 4; ++b)
        for (int k = 0; k < NB; ++k) {
            float dd = Y[((size_t)b * 128 + c) * NB + k] - mean;
            v = fmaf(dd, dd, v);
        }
    float var = v / (float)n;
    float sc = conv_g[d * 128 + c] * rsqrtf(var + 1e-5f);
    ws[SCALED_OFF + tid] = sc;
    ws[SHIFTD_OFF + tid] = conv_b[d * 128 + c] - mean * sc;
}

// K3c: contrib[b][o][blk3]. grid = B*64, block 128 (thread = o)
__global__ __launch_bounds__(128) void k_contrib(const float* __restrict__ final_w,
                                                 float* __restrict__ ws) {
    int b = blockIdx.x >> 6, blk3 = blockIdx.x & 63;
    int i3 = blk3 >> 3, j3 = blk3 & 7;
    __shared__ float pn[512];
    int t = threadIdx.x;
    for (int k = t; k < 512; k += 128) {
        int d = k >> 7, c = k & 127;
        int sh = 3 - d;
        int blkd = (i3 >> sh) * (1 << d) + (j3 >> sh);
        int NB = 1 << (2 * d);
        float yv = ws[YBASE_ + level_rel(d) + ((size_t)b * 128 + c) * NB + blkd];
        pn[k] = yv * ws[SCALED_OFF + k] + ws[SHIFTD_OFF + k];
    }
    __syncthreads();
    const float* fw = final_w + (size_t)t * 640 + 128;
    float acc = 0.f;
#pragma unroll 8
    for (int k = 0; k < 512; k += 4) {
        float4 f = *(const float4*)(fw + k);
        acc = fmaf(pn[k], f.x, acc);
        acc = fmaf(pn[k + 1], f.y, acc);
        acc = fmaf(pn[k + 2], f.z, acc);
        acc = fmaf(pn[k + 3], f.w, acc);
    }
    ws[CONTRIB_OFF + ((size_t)b * 128 + t) * 64 + blk3] = acc;
}

// K4: closed-form final BN stats: sum(z^2) = wGw + 2*sum_blk cv*(w.S3) + 1024*sum cv^2
// grid = 128 (o), block 128 (t = c)
__global__ __launch_bounds__(128) void k_stats(const float* __restrict__ final_w,
                                               const float* __restrict__ final_g,
                                               const float* __restrict__ final_b,
                                               float* __restrict__ ws) {
    int o = blockIdx.x, t = threadIdx.x;
    __shared__ __align__(16) float wlds[128];
    __shared__ __align__(16) float cvl[64];
    __shared__ float rbuf[4];
    wlds[t] = final_w[(size_t)o * 640 + t];
    __syncthreads();
    float SSQ = 0.f, SUM = 0.f;
    for (int b = 0; b < 4; ++b) {
        if (t < 64) cvl[t] = ws[CONTRIB_OFF + (size_t)(b * 128 + o) * 64 + t];
        __syncthreads();
        const float* Gb = ws + G_OFF + (size_t)b * 16384 + (size_t)t * 128;
        float a1 = 0.f;
#pragma unroll 8
        for (int k = 0; k < 128; k += 4) {
            float4 g = *(const float4*)(Gb + k);
            float4 w = *(const float4*)(&wlds[k]);
            a1 = fmaf(g.x, w.x, fmaf(g.y, w.y, fmaf(g.z, w.z, fmaf(g.w, w.w, a1))));
        }
        const float* S3p = ws + S3_OFF + (size_t)(b * 128 + t) * 64;
        float a2 = 0.f;
#pragma unroll 8
        for (int k = 0; k < 64; k += 4) {
            float4 sv = *(const float4*)(S3p + k);
            float4 cv = *(const float4*)(&cvl[k]);
            a2 = fmaf(sv.x, cv.x, fmaf(sv.y, cv.y, fmaf(sv.z, cv.z, fmaf(sv.w, cv.w, a2))));
        }
        float r1 = (a1 + 2.f * a2) * wlds[t];
        float r2 = wlds[t] * ws[SX_OFF + b * 128 + t];
        if (t < 64) {
            r1 += 1024.f * cvl[t] * cvl[t];
            r2 += 1024.f * cvl[t];
        }
#pragma unroll
        for (int k = 1; k < 64; k <<= 1) {
            r1 += __shfl_xor(r1, k);
            r2 += __shfl_xor(r2, k);
        }
        if ((t & 63) == 0) {
            rbuf[(t >> 6) * 2] = r1;
            rbuf[(t >> 6) * 2 + 1] = r2;
        }
        __syncthreads();
        SSQ += rbuf[0] + rbuf[2];
        SUM += rbuf[1] + rbuf[3];
        __syncthreads();
    }
    if (t == 0) {
        float mean = SUM / 262144.f;
        float var = SSQ / 262144.f - mean * mean;
        float sc = final_g[o] * rsqrtf(var + 1e-5f);
        ws[SCALEF_OFF + o] = sc;
        ws[SHIFTF_OFF + o] = final_b[o] - mean * sc;
    }
}

// K5: out[b,o,p] = (MFMA(W0,x) + contrib) * scale[o] + shift[o].
// grid = 2048 (b*512 + ptile of 128), block 256 (4 waves; wave = 32 p)
__global__ __launch_bounds__(256) void k_out(const float* __restrict__ x,
                                             const float* __restrict__ final_w,
                                             const float* __restrict__ ws,
                                             float* __restrict__ out) {
    __shared__ uint4 wtileq[2048];  // [128 o][128 c] bf16, swizzled, 32KB
    __shared__ float scl[128], shf[128], cvs[512];
    unsigned char* wtile = (unsigned char*)wtileq;
    int wgid = blockIdx.x;
    int b = wgid >> 9, pt = wgid & 511;
    int p0 = pt * 128;
    int t = threadIdx.x, l = t & 63, wv = t >> 6;
#pragma unroll
    for (int it = 0; it < 32; ++it) {
        int pid = it * 256 + t;  // 8192 pairs
        int o = pid >> 6, cp = (pid & 63) * 2;
        float2 f = *(const float2*)(final_w + (size_t)o * 640 + cp);
        unsigned int u = bfpair(f.x, f.y);
        int wa = (o * 256 + cp * 2) ^ ((o & 7) << 4);
        *(unsigned int*)(wtile + wa) = u;
    }
    if (t < 128) {
        scl[t] = ws[SCALEF_OFF + t];
        shf[t] = ws[SHIFTF_OFF + t];
    }
    int i3 = pt >> 6, jb = (pt & 1) * 4;
    for (int q = t; q < 512; q += 256) {
        int o = q >> 2, jj = q & 3;
        cvs[q] = ws[CONTRIB_OFF + (size_t)(b * 128 + o) * 64 + i3 * 8 + jb + jj];
    }
    __syncthreads();

    const float* xb = x + (size_t)b * C_ * P_;
    int pw = p0 + wv * 32;
    f32x4 acc[8][2];
#pragma unroll
    for (int i = 0; i < 8; ++i) {
        acc[i][0] = (f32x4){0.f, 0.f, 0.f, 0.f};
        acc[i][1] = (f32x4){0.f, 0.f, 0.f, 0.f};
    }
#pragma unroll
    for (int ks = 0; ks < 4; ++ks) {
        short8 bf[2];
#pragma unroll
        for (int nt = 0; nt < 2; ++nt) {
            const float* xp = xb + (size_t)(ks * 32 + (l >> 4) * 8) * P_ + (pw + nt * 16 + (l & 15));
            float f0 = xp[0 * P_], f1 = xp[1 * P_], f2 = xp[2 * P_], f3 = xp[3 * P_];
            float f4 = xp[4 * P_], f5 = xp[5 * P_], f6 = xp[6 * P_], f7 = xp[7 * P_];
            union { uint4 u; short8 s; } cvtu;
            cvtu.u = make_uint4(bfpair(f0, f1), bfpair(f2, f3), bfpair(f4, f5), bfpair(f6, f7));
            bf[nt] = cvtu.s;
        }
#pragma unroll
        for (int mt = 0; mt < 8; ++mt) {
            int ra = ((mt * 16 + (l & 15)) * 256 + ks * 64 + (l >> 4) * 16) ^ ((l & 7) << 4);
            short8 af = *(const short8*)(wtile + ra);
            acc[mt][0] = __builtin_amdgcn_mfma_f32_16x16x32_bf16(af, bf[0], acc[mt][0], 0, 0, 0);
            acc[mt][1] = __builtin_amdgcn_mfma_f32_16x16x32_bf16(af, bf[1], acc[mt][1], 0, 0, 0);
        }
    }
#pragma unroll
    for (int mt = 0; mt < 8; ++mt)
#pragma unroll
        for (int nt = 0; nt < 2; ++nt) {
            int p = pw + nt * 16 + (l & 15);
            int jj = ((p & 255) >> 5) & 3;
#pragma unroll
            for (int r = 0; r < 4; ++r) {
                int o = mt * 16 + (l >> 4) * 4 + r;
                float z = acc[mt][nt][r] + cvs[o * 4 + jj];
                out[(size_t)(b * 128 + o) * P_ + p] = fmaf(z, scl[o], shf[o]);
            }
        }
}

extern "C" void kernel_launch(void* const* d_in, const int* in_sizes, int n_in,
                              void* d_out, int out_size, void* d_ws, size_t ws_size,
                              hipStream_t stream) {
    const float* x = (const float*)d_in[0];
    const float* conv_w = (const float*)d_in[1];
    const float* conv_g = (const float*)d_in[2];
    const float* conv_b = (const float*)d_in[3];
    const float* final_w = (const float*)d_in[4];
    const float* final_g = (const float*)d_in[5];
    const float* final_b = (const float*)d_in[6];
    float* out = (float*)d_out;
    float* ws = (float*)d_ws;

    // single fused pass over x: fp32-exact block max/sum partials + bf16 Gram
    // (Gram partials live in d_out scratch until k_reduceG; k_out overwrites d_out)
    k_gram_pool<<<512, 512, 0, stream>>>(x, ws, out);
    k_reduceG<<<256, 256, 0, stream>>>(out, ws);
    k_reduceMS<<<512, 256, 0, stream>>>(ws);
    k_conv_pool<<<64, 256, 0, stream>>>(conv_w, ws);
    k_bnstats_d<<<2, 256, 0, stream>>>(conv_g, conv_b, ws);
    k_contrib<<<B_ * 64, 128, 0, stream>>>(final_w, ws);
    k_stats<<<128, 128, 0, stream>>>(final_w, final_g, final_b, ws);
    k_out<<<2048, 256, 0, stream>>>(x, final_w, ws, out);
}

// Round 12
// 239.576 us; speedup vs baseline: 1.0865x; 1.0865x over previous
//
#include <hip/hip_runtime.h>
#include <hip/hip_bf16.h>
#include <math.h>
#include <float.h>

// x: [4,128,256,256] f32; conv_w: [4,128,128]; conv_g/b: [4,128]
// final_w: [128,640]; final_g/b: [128]; out: [4,128,256,256] f32
#define B_ 4
#define C_ 128
#define P_ 65536

// ---- workspace float offsets ----
#define M3_OFF      0        // [512][64] block maxima (32x32), exact fp32
#define M2_OFF      32768    // [512][16]
#define M1_OFF      40960    // [512][4]
#define M0_OFF      43008    // [512]
#define YBASE_      43520    // y levels, same internal layout as M
#define SCALED_OFF  87040    // [4][128]
#define SHIFTD_OFF  87552    // [4][128]
#define CONTRIB_OFF 88064    // [4][128][64]
#define S3_OFF      120832   // [512][64] block sums (32x32), exact fp32
#define SX_OFF      153600   // [512] per-(b,c) total sum
#define G_OFF       154112   // [4][128][128] Gram (bf16-sourced, fp32 accum)
#define SCALEF_OFF  219648   // [128]
#define SHIFTF_OFF  219776   // [128]
#define MAXP_OFF    219904   // [512 bc][64 blk][32 rr] fp32 max partials
#define SUMP_OFF    1268480  // [512 bc][64 blk][32 rr] fp32 sum partials
// total floats: 2317056 (~8.8 MB)

using short8 = __attribute__((ext_vector_type(8))) short;
using f32x4 = __attribute__((ext_vector_type(4))) float;
using f32x16 = __attribute__((ext_vector_type(16))) float;

__device__ __forceinline__ int level_rel(int d) {
    return YBASE_ - 512 * (((1 << (2 * (d + 1))) - 1) / 3);
}

// RNE pack of two f32 into bf16x2 (low = first arg) — hardware v_cvt_pk_bf16_f32
__device__ __forceinline__ unsigned int bfpair(float a, float b) {
    union { __hip_bfloat162 h2; unsigned int u; } cv;
    cv.h2 = __float22bfloat162_rn(make_float2(a, b));
    return cv.u;
}

#define GLDS16(src, dst)                                                    \
    __builtin_amdgcn_global_load_lds(                                       \
        (const __attribute__((address_space(1))) unsigned int*)(src),       \
        (__attribute__((address_space(3))) unsigned int*)(dst), 16, 0, 0)

// K1: fused pass over x. Grid 1024 (4 WG/CU for cross-WG overlap): WG = one
// image row (b, rw); [128 c][32 px] fp32 tiles, double-buffered (32 KB LDS),
// staged via global_load_lds (slot-XOR swizzle on the global source; linear
// LDS dest). 8 phases; per phase: issue next tile, compute Gram MFMAs
// (32x32x16, v_cvt_pk conversion), exact fp32 block max/sum folded into
// waves 0-3's A-side fragment loads (BEFORE rounding), one __syncthreads.
// Wave w: G-quadrants (w&3, 2*(w>>2)+{0,1}). block 512.
__global__ __launch_bounds__(512, 8) void k_gram_pool(const float* __restrict__ x,
                                                      float* __restrict__ ws,
                                                      float* __restrict__ gpart) {
    __shared__ float buf[2][4096];  // 2 x 16 KB; LDS[r][slot] = glob[r][slot ^ (r&7)]
    int wg = blockIdx.x;
    int b = wg >> 8, rw = wg & 255;  // rw = image row (256 px)
    const float* xb = x + (size_t)b * C_ * P_ + (size_t)rw * 256;
    int t_ = threadIdx.x, l = t_ & 63, wv = t_ >> 6;
    int qi = wv & 3;            // A quadrant-row
    int qjb = (wv >> 2) * 2;    // B quadrant-col base (2 quadrants per wave)
    bool doacc = (wv < 4);      // waves 0-3 own rows 32*qi..+32 max/sum
    int lrow = l >> 3, lch = l & 7;

    f32x16 acc[2];
#pragma unroll
    for (int j = 0; j < 2; ++j)
#pragma unroll
        for (int r = 0; r < 16; ++r) acc[j][r] = 0.f;
    float mxA[8], smA[8];  // per 32-px col block (jc == phase)
#pragma unroll
    for (int j = 0; j < 8; ++j) { mxA[j] = -FLT_MAX; smA[j] = 0.f; }

    // per-wave stage of tile tt: 2 gload_lds, each = 8 rows x 128 B
#define ISSUE(tt)                                                            \
    do {                                                                     \
        _Pragma("unroll") for (int i_ = 0; i_ < 2; ++i_) {                   \
            int row_ = wv * 16 + i_ * 8 + lrow;                              \
            int ch_ = lch ^ (row_ & 7);                                      \
            GLDS16(xb + (size_t)row_ * P_ + (tt) * 32 + ch_ * 4,             \
                   &buf[(tt) & 1][(wv * 16 + i_ * 8) * 32]);                 \
        }                                                                    \
    } while (0)

    ISSUE(0);
    __syncthreads();  // drain: tile 0 ready

#pragma unroll
    for (int t = 0; t < 8; ++t) {
        if (t < 7) ISSUE(t + 1);  // transfer overlaps compute below
        const float* tl = &buf[t & 1][0];
        int jc = t;  // this tile IS col-block t of row rw
#pragma unroll
        for (int ks = 0; ks < 2; ++ks) {
            int ch = ks * 4 + ((l >> 5) << 1);
            // A fragment (+ exact fp32 max/sum on waves 0-3)
            short8 fa;
            {
                int row = qi * 32 + (l & 31);
                int sw = row & 7;
                float4 v0 = *(const float4*)(tl + row * 32 + ((ch ^ sw) << 2));
                float4 v1 = *(const float4*)(tl + row * 32 + (((ch + 1) ^ sw) << 2));
                if (doacc) {
                    mxA[jc] = fmaxf(mxA[jc],
                        fmaxf(fmaxf(fmaxf(v0.x, v0.y), fmaxf(v0.z, v0.w)),
                              fmaxf(fmaxf(v1.x, v1.y), fmaxf(v1.z, v1.w))));
                    smA[jc] += ((v0.x + v0.y) + (v0.z + v0.w)) +
                               ((v1.x + v1.y) + (v1.z + v1.w));
                }
                union { uint4 u; short8 s8; } cu;
                cu.u = make_uint4(bfpair(v0.x, v0.y), bfpair(v0.z, v0.w),
                                  bfpair(v1.x, v1.y), bfpair(v1.z, v1.w));
                fa = cu.s8;
            }
#pragma unroll
            for (int j = 0; j < 2; ++j) {
                int row = (qjb + j) * 32 + (l & 31);
                int sw = row & 7;
                float4 v0 = *(const float4*)(tl + row * 32 + ((ch ^ sw) << 2));
                float4 v1 = *(const float4*)(tl + row * 32 + (((ch + 1) ^ sw) << 2));
                union { uint4 u; short8 s8; } cu;
                cu.u = make_uint4(bfpair(v0.x, v0.y), bfpair(v0.z, v0.w),
                                  bfpair(v1.x, v1.y), bfpair(v1.z, v1.w));
                acc[j] = __builtin_amdgcn_mfma_f32_32x32x16_bf16(fa, cu.s8, acc[j], 0, 0, 0);
            }
        }
        __syncthreads();  // drains next-tile loads + guards buffer reuse
    }
#undef ISSUE

    // ---- write Gram partials [wg][128][128] (G symmetric -> layout-safe) ----
    size_t gb = (size_t)wg * 16384;
#pragma unroll
    for (int j = 0; j < 2; ++j)
#pragma unroll
        for (int r = 0; r < 16; ++r) {
            int row = qi * 32 + (r & 3) + 8 * (r >> 2) + 4 * (l >> 5);
            int col = (qjb + j) * 32 + (l & 31);
            gpart[gb + (size_t)row * 128 + col] = acc[j][r];
        }
    // ---- max/sum epilogue: combine lane-halves, write [bc][blk][32 rr] ----
    if (doacc) {
        int i3 = rw >> 5, rr = rw & 31;
#pragma unroll
        for (int jc = 0; jc < 8; ++jc) {
            float m = mxA[jc], sv = smA[jc];
            m = fmaxf(m, __shfl_xor(m, 32));
            sv += __shfl_xor(sv, 32);
            if (l < 32) {
                int c = qi * 32 + l;
                size_t idx = ((size_t)(b * 128 + c) * 64 + i3 * 8 + jc) * 32 + rr;
                ws[MAXP_OFF + idx] = m;
                ws[SUMP_OFF + idx] = sv;
            }
        }
    }
}

// K2a: reduce Gram partials over 256 row-slices per b. grid = 256, block 256
__global__ __launch_bounds__(256) void k_reduceG(const float* __restrict__ gpart,
                                                 float* __restrict__ ws) {
    int tid = blockIdx.x * 256 + threadIdx.x;  // 65536
    int b = tid >> 14, inner = tid & 16383;
    const float* p = gpart + (size_t)b * 256 * 16384 + inner;
    float s = 0.f;
    for (int r = 0; r < 256; ++r) s += p[(size_t)r * 16384];
    ws[G_OFF + tid] = s;
}

// K2b: reduce max/sum partials (32 per blk) -> M3/S3/SX + pyramid.
// grid = 512 (bc), block 256; thread quad (blk, q) loads 8 contiguous rr.
__global__ __launch_bounds__(256) void k_reduceMS(float* __restrict__ ws) {
    int bc = blockIdx.x;  // 512
    int t = threadIdx.x;
    int blk = t >> 2, q = t & 3;
    __shared__ float bm[64], bs[64];
    __shared__ float lv[24];
    __shared__ float sxr[8];
    {
        size_t base = (size_t)bc * 2048 + blk * 32 + q * 8;
        float4 m0 = *(const float4*)(ws + MAXP_OFF + base);
        float4 m1 = *(const float4*)(ws + MAXP_OFF + base + 4);
        float4 s0 = *(const float4*)(ws + SUMP_OFF + base);
        float4 s1 = *(const float4*)(ws + SUMP_OFF + base + 4);
        float m = fmaxf(fmaxf(fmaxf(m0.x, m0.y), fmaxf(m0.z, m0.w)),
                        fmaxf(fmaxf(m1.x, m1.y), fmaxf(m1.z, m1.w)));
        float s = (((s0.x + s0.y) + (s0.z + s0.w)) + ((s1.x + s1.y) + (s1.z + s1.w)));
        m = fmaxf(m, __shfl_xor(m, 1)); s += __shfl_xor(s, 1);
        m = fmaxf(m, __shfl_xor(m, 2)); s += __shfl_xor(s, 2);
        if (q == 0) {
            bm[blk] = m;
            bs[blk] = s;
            ws[M3_OFF + (size_t)bc * 64 + blk] = m;
            ws[S3_OFF + (size_t)bc * 64 + blk] = s;
        }
    }
    __syncthreads();
    if (t < 8) {
        float sx = 0.f;
        for (int r = 0; r < 8; ++r) sx += bs[t * 8 + r];
        sxr[t] = sx;
    }
    if (t < 16) {
        int i2 = t >> 2, j2 = t & 3;
        float m = -FLT_MAX;
        for (int a = 0; a < 2; ++a)
            for (int b2 = 0; b2 < 2; ++b2)
                m = fmaxf(m, bm[(2 * i2 + a) * 8 + 2 * j2 + b2]);
        lv[t] = m;
        ws[M2_OFF + (size_t)bc * 16 + t] = m;
    }
    __syncthreads();
    if (t == 0) {
        float sx = 0.f;
        for (int r = 0; r < 8; ++r) sx += sxr[r];
        ws[SX_OFF + bc] = sx;
    }
    if (t < 4) {
        int i1 = t >> 1, j1 = t & 1;
        float m = -FLT_MAX;
        for (int a = 0; a < 2; ++a)
            for (int b2 = 0; b2 < 2; ++b2)
                m = fmaxf(m, lv[(2 * i1 + a) * 4 + 2 * j1 + b2]);
        lv[16 + t] = m;
        ws[M1_OFF + (size_t)bc * 4 + t] = m;
    }
    __syncthreads();
    if (t == 0)
        ws[M0_OFF + bc] = fmaxf(fmaxf(lv[16], lv[17]), fmaxf(lv[18], lv[19]));
}

// K3a: y_d[b,co,blk] = sum_ci M_d[b,ci,blk] * conv_w[d][co][ci]
__global__ __launch_bounds__(256) void k_conv_pool(const float* __restrict__ conv_w,
                                                   float* __restrict__ ws) {
    int bid = blockIdx.x;
    int d = bid >> 4, b = (bid >> 2) & 3, cchunk = bid & 3;
    int NB = 1 << (2 * d);
    int rel = level_rel(d);
    const float* Mb = ws + rel + (size_t)b * 128 * NB;
    float* Yb = ws + YBASE_ + rel + (size_t)b * 128 * NB;
    __shared__ float mlds[8192];
    int t = threadIdx.x;
    int tot = 128 * NB;
    for (int i = t; i < tot; i += 256) mlds[i] = Mb[i];
    __syncthreads();
    if (NB >= 4) {
        int nbq = NB >> 2;
        int nq = 32 * nbq;
        for (int qi = t; qi < nq; qi += 256) {
            int co = cchunk * 32 + (qi >> (2 * d - 2));
            int bq = qi & (nbq - 1);
            const float* wrow = conv_w + ((size_t)d * 128 + co) * 128;
            float a0 = 0.f, a1 = 0.f, a2 = 0.f, a3 = 0.f;
            for (int ci = 0; ci < 128; ++ci) {
                float4 mv = *(const float4*)(&mlds[ci * NB + bq * 4]);
                float wvv = wrow[ci];
                a0 = fmaf(wvv, mv.x, a0);
                a1 = fmaf(wvv, mv.y, a1);
                a2 = fmaf(wvv, mv.z, a2);
                a3 = fmaf(wvv, mv.w, a3);
            }
            float4 r;
            r.x = a0; r.y = a1; r.z = a2; r.w = a3;
            *(float4*)(&Yb[co * NB + bq * 4]) = r;
        }
    } else {
        for (int oi = t; oi < 32; oi += 256) {
            int co = cchunk * 32 + oi;
            const float* wrow = conv_w + (size_t)co * 128;
            float acc = 0.f;
            for (int ci = 0; ci < 128; ++ci) acc = fmaf(mlds[ci], wrow[ci], acc);
            Yb[co] = acc;
        }
    }
}

// K3b: per-(d,c) BN stats
__global__ __launch_bounds__(256) void k_bnstats_d(const float* __restrict__ conv_g,
                                                   const float* __restrict__ conv_b,
                                                   float* __restrict__ ws) {
    int tid = blockIdx.x * 256 + threadIdx.x;
    if (tid >= 512) return;
    int d = tid >> 7, c = tid & 127;
    int NB = 1 << (2 * d);
    const float* Y = ws + YBASE_ + level_rel(d);
    int n = 4 * NB;
    float s = 0.f;
    for (int b = 0; b < 4; ++b)
        for (int k = 0; k < NB; ++k) s += Y[((size_t)b * 128 + c) * NB + k];
    float mean = s / (float)n;
    float v = 0.f;
    for (int b = 0; b < 4; ++b)
        for (int k = 0; k < NB; ++k) {
            float dd = Y[((size_t)b * 128 + c) * NB + k] - mean;
            v = fmaf(dd, dd, v);
        }
    float var = v / (float)n;
    float sc = conv_g[d * 128 + c] * rsqrtf(var + 1e-5f);
    ws[SCALED_OFF + tid] = sc;
    ws[SHIFTD_OFF + tid] = conv_b[d * 128 + c] - mean * sc;
}

// K3c: contrib[b][o][blk3]. grid = B*64, block 128 (thread = o)
__global__ __launch_bounds__(128) void k_contrib(const float* __restrict__ final_w,
                                                 float* __restrict__ ws) {
    int b = blockIdx.x >> 6, blk3 = blockIdx.x & 63;
    int i3 = blk3 >> 3, j3 = blk3 & 7;
    __shared__ float pn[512];
    int t = threadIdx.x;
    for (int k = t; k < 512; k += 128) {
        int d = k >> 7, c = k & 127;
        int sh = 3 - d;
        int blkd = (i3 >> sh) * (1 << d) + (j3 >> sh);
        int NB = 1 << (2 * d);
        float yv = ws[YBASE_ + level_rel(d) + ((size_t)b * 128 + c) * NB + blkd];
        pn[k] = yv * ws[SCALED_OFF + k] + ws[SHIFTD_OFF + k];
    }
    __syncthreads();
    const float* fw = final_w + (size_t)t * 640 + 128;
    float acc = 0.f;
#pragma unroll 8
    for (int k = 0; k < 512; k += 4) {
        float4 f = *(const float4*)(fw + k);
        acc = fmaf(pn[k], f.x, acc);
        acc = fmaf(pn[k + 1], f.y, acc);
        acc = fmaf(pn[k + 2], f.z, acc);
        acc = fmaf(pn[k + 3], f.w, acc);
    }
    ws[CONTRIB_OFF + ((size_t)b * 128 + t) * 64 + blk3] = acc;
}

// K4: closed-form final BN stats: sum(z^2) = wGw + 2*sum_blk cv*(w.S3) + 1024*sum cv^2
// grid = 128 (o), block 128 (t = c)
__global__ __launch_bounds__(128) void k_stats(const float* __restrict__ final_w,
                                               const float* __restrict__ final_g,
                                               const float* __restrict__ final_b,
                                               float* __restrict__ ws) {
    int o = blockIdx.x, t = threadIdx.x;
    __shared__ __align__(16) float wlds[128];
    __shared__ __align__(16) float cvl[64];
    __shared__ float rbuf[4];
    wlds[t] = final_w[(size_t)o * 640 + t];
    __syncthreads();
    float SSQ = 0.f, SUM = 0.f;
    for (int b = 0; b < 4; ++b) {
        if (t < 64) cvl[t] = ws[CONTRIB_OFF + (size_t)(b * 128 + o) * 64 + t];
        __syncthreads();
        const float* Gb = ws + G_OFF + (size_t)b * 16384 + (size_t)t * 128;
        float a1 = 0.f;
#pragma unroll 8
        for (int k = 0; k < 128; k += 4) {
            float4 g = *(const float4*)(Gb + k);
            float4 w = *(const float4*)(&wlds[k]);
            a1 = fmaf(g.x, w.x, fmaf(g.y, w.y, fmaf(g.z, w.z, fmaf(g.w, w.w, a1))));
        }
        const float* S3p = ws + S3_OFF + (size_t)(b * 128 + t) * 64;
        float a2 = 0.f;
#pragma unroll 8
        for (int k = 0; k < 64; k += 4) {
            float4 sv = *(const float4*)(S3p + k);
            float4 cv = *(const float4*)(&cvl[k]);
            a2 = fmaf(sv.x, cv.x, fmaf(sv.y, cv.y, fmaf(sv.z, cv.z, fmaf(sv.w, cv.w, a2))));
        }
        float r1 = (a1 + 2.f * a2) * wlds[t];
        float r2 = wlds[t] * ws[SX_OFF + b * 128 + t];
        if (t < 64) {
            r1 += 1024.f * cvl[t] * cvl[t];
            r2 += 1024.f * cvl[t];
        }
#pragma unroll
        for (int k = 1; k < 64; k <<= 1) {
            r1 += __shfl_xor(r1, k);
            r2 += __shfl_xor(r2, k);
        }
        if ((t & 63) == 0) {
            rbuf[(t >> 6) * 2] = r1;
            rbuf[(t >> 6) * 2 + 1] = r2;
        }
        __syncthreads();
        SSQ += rbuf[0] + rbuf[2];
        SUM += rbuf[1] + rbuf[3];
        __syncthreads();
    }
    if (t == 0) {
        float mean = SUM / 262144.f;
        float var = SSQ / 262144.f - mean * mean;
        float sc = final_g[o] * rsqrtf(var + 1e-5f);
        ws[SCALEF_OFF + o] = sc;
        ws[SHIFTF_OFF + o] = final_b[o] - mean * sc;
    }
}

// K5: out[b,o,p] = (MFMA(W0,x) + contrib) * scale[o] + shift[o].
// grid = 2048 (b*512 + ptile of 128), block 256 (4 waves; wave = 32 p)
__global__ __launch_bounds__(256) void k_out(const float* __restrict__ x,
                                             const float* __restrict__ final_w,
                                             const float* __restrict__ ws,
                                             float* __restrict__ out) {
    __shared__ uint4 wtileq[2048];  // [128 o][128 c] bf16, swizzled, 32KB
    __shared__ float scl[128], shf[128], cvs[512];
    unsigned char* wtile = (unsigned char*)wtileq;
    int wgid = blockIdx.x;
    int b = wgid >> 9, pt = wgid & 511;
    int p0 = pt * 128;
    int t = threadIdx.x, l = t & 63, wv = t >> 6;
#pragma unroll
    for (int it = 0; it < 32; ++it) {
        int pid = it * 256 + t;  // 8192 pairs
        int o = pid >> 6, cp = (pid & 63) * 2;
        float2 f = *(const float2*)(final_w + (size_t)o * 640 + cp);
        unsigned int u = bfpair(f.x, f.y);
        int wa = (o * 256 + cp * 2) ^ ((o & 7) << 4);
        *(unsigned int*)(wtile + wa) = u;
    }
    if (t < 128) {
        scl[t] = ws[SCALEF_OFF + t];
        shf[t] = ws[SHIFTF_OFF + t];
    }
    int i3 = pt >> 6, jb = (pt & 1) * 4;
    for (int q = t; q < 512; q += 256) {
        int o = q >> 2, jj = q & 3;
        cvs[q] = ws[CONTRIB_OFF + (size_t)(b * 128 + o) * 64 + i3 * 8 + jb + jj];
    }
    __syncthreads();

    const float* xb = x + (size_t)b * C_ * P_;
    int pw = p0 + wv * 32;
    f32x4 acc[8][2];
#pragma unroll
    for (int i = 0; i < 8; ++i) {
        acc[i][0] = (f32x4){0.f, 0.f, 0.f, 0.f};
        acc[i][1] = (f32x4){0.f, 0.f, 0.f, 0.f};
    }
#pragma unroll
    for (int ks = 0; ks < 4; ++ks) {
        short8 bf[2];
#pragma unroll
        for (int nt = 0; nt < 2; ++nt) {
            const float* xp = xb + (size_t)(ks * 32 + (l >> 4) * 8) * P_ + (pw + nt * 16 + (l & 15));
            float f0 = xp[0 * P_], f1 = xp[1 * P_], f2 = xp[2 * P_], f3 = xp[3 * P_];
            float f4 = xp[4 * P_], f5 = xp[5 * P_], f6 = xp[6 * P_], f7 = xp[7 * P_];
            union { uint4 u; short8 s; } cvtu;
            cvtu.u = make_uint4(bfpair(f0, f1), bfpair(f2, f3), bfpair(f4, f5), bfpair(f6, f7));
            bf[nt] = cvtu.s;
        }
#pragma unroll
        for (int mt = 0; mt < 8; ++mt) {
            int ra = ((mt * 16 + (l & 15)) * 256 + ks * 64 + (l >> 4) * 16) ^ ((l & 7) << 4);
            short8 af = *(const short8*)(wtile + ra);
            acc[mt][0] = __builtin_amdgcn_mfma_f32_16x16x32_bf16(af, bf[0], acc[mt][0], 0, 0, 0);
            acc[mt][1] = __builtin_amdgcn_mfma_f32_16x16x32_bf16(af, bf[1], acc[mt][1], 0, 0, 0);
        }
    }
#pragma unroll
    for (int mt = 0; mt < 8; ++mt)
#pragma unroll
        for (int nt = 0; nt < 2; ++nt) {
            int p = pw + nt * 16 + (l & 15);
            int jj = ((p & 255) >> 5) & 3;
#pragma unroll
            for (int r = 0; r < 4; ++r) {
                int o = mt * 16 + (l >> 4) * 4 + r;
                float z = acc[mt][nt][r] + cvs[o * 4 + jj];
                out[(size_t)(b * 128 + o) * P_ + p] = fmaf(z, scl[o], shf[o]);
            }
        }
}

extern "C" void kernel_launch(void* const* d_in, const int* in_sizes, int n_in,
                              void* d_out, int out_size, void* d_ws, size_t ws_size,
                              hipStream_t stream) {
    const float* x = (const float*)d_in[0];
    const float* conv_w = (const float*)d_in[1];
    const float* conv_g = (const float*)d_in[2];
    const float* conv_b = (const float*)d_in[3];
    const float* final_w = (const float*)d_in[4];
    const float* final_g = (const float*)d_in[5];
    const float* final_b = (const float*)d_in[6];
    float* out = (float*)d_out;
    float* ws = (float*)d_ws;

    // single fused pass over x: fp32-exact block max/sum partials + bf16 Gram
    // (Gram partials live in d_out scratch until k_reduceG; k_out overwrites d_out)
    k_gram_pool<<<1024, 512, 0, stream>>>(x, ws, out);
    k_reduceG<<<256, 256, 0, stream>>>(out, ws);
    k_reduceMS<<<512, 256, 0, stream>>>(ws);
    k_conv_pool<<<64, 256, 0, stream>>>(conv_w, ws);
    k_bnstats_d<<<2, 256, 0, stream>>>(conv_g, conv_b, ws);
    k_contrib<<<B_ * 64, 128, 0, stream>>>(final_w, ws);
    k_stats<<<128, 128, 0, stream>>>(final_w, final_g, final_b, ws);
    k_out<<<2048, 256, 0, stream>>>(x, final_w, ws, out);
}

// Round 13
// 199.956 us; speedup vs baseline: 1.3017x; 1.1981x over previous
//
#include <hip/hip_runtime.h>
#include <hip/hip_bf16.h>
#include <math.h>
#include <float.h>

// x: [4,128,256,256] f32; conv_w: [4,128,128]; conv_g/b: [4,128]
// final_w: [128,640]; final_g/b: [128]; out: [4,128,256,256] f32
#define B_ 4
#define C_ 128
#define P_ 65536

// ---- workspace float offsets ----
#define M3_OFF      0        // [512][64] block maxima (32x32), exact fp32
#define M2_OFF      32768    // [512][16]
#define M1_OFF      40960    // [512][4]
#define M0_OFF      43008    // [512]
#define YBASE_      43520    // y levels, same internal layout as M
#define SCALED_OFF  87040    // [4][128]
#define SHIFTD_OFF  87552    // [4][128]
#define CONTRIB_OFF 88064    // [4][128][64]
#define S3_OFF      120832   // [512][64] block sums (32x32), exact fp32
#define SX_OFF      153600   // [512] per-(b,c) total sum
#define G_OFF       154112   // [4][128][128] Gram (bf16-sourced, fp32 accum)
#define SCALEF_OFF  219648   // [128]
#define SHIFTF_OFF  219776   // [128]
#define MAXP_OFF    219904   // [512 wg][2 half][128 c][8 j3] fp32 max partials (wg-major = coalesced writes)
#define SUMP_OFF    1268480  // same layout
// total floats: 2317056 (~8.8 MB)

using short8 = __attribute__((ext_vector_type(8))) short;
using f32x4 = __attribute__((ext_vector_type(4))) float;
using f32x16 = __attribute__((ext_vector_type(16))) float;

__device__ __forceinline__ int level_rel(int d) {
    return YBASE_ - 512 * (((1 << (2 * (d + 1))) - 1) / 3);
}

// RNE pack of two f32 into bf16x2 (low = first arg) — hardware v_cvt_pk_bf16_f32
__device__ __forceinline__ unsigned int bfpair(float a, float b) {
    union { __hip_bfloat162 h2; unsigned int u; } cv;
    cv.h2 = __float22bfloat162_rn(make_float2(a, b));
    return cv.u;
}

// K1: fused pass over x. Grid 512 (b*128 + rc; rc = 2 image rows = 512 px),
// block 512 (8 waves). Double-buffered [128 c][64 px] bf16 LDS tile (32 KB),
// register-staged with coalesced 256B-per-row float4 loads; fp32 max/sum
// computed on the registers BEFORE bf16 rounding, shuffle-reduced per 32-px
// block and written per phase (wg-major layout, coalesced). Convert once via
// v_cvt_pk; Gram fragments are single ds_read_b128 from the swizzled bf16
// tile. Wave w computes G-quadrants (w&3, 2*(w>>2)+{0,1}) via 32x32x16 MFMA.
__global__ __launch_bounds__(512, 4) void k_gram_pool(const float* __restrict__ x,
                                                      float* __restrict__ ws,
                                                      float* __restrict__ gpart) {
    __shared__ __align__(16) unsigned short buf[2][8192];  // 2 x [128 c][64 px] bf16, swizzled
    int wg = blockIdx.x;
    int b = wg >> 7, rc = wg & 127;
    const float* xb = x + (size_t)b * C_ * P_ + (size_t)rc * 512;
    int t_ = threadIdx.x, l = t_ & 63, wv = t_ >> 6;
    int qi = wv & 3;            // A quadrant-row
    int qjb = (wv >> 2) * 2;    // B quadrant-col base
    int srow0 = wv * 16 + (l >> 4);  // staging channel (+ i*4)
    int spx = (l & 15) * 4;          // staging px within 64-px tile
    float4 ld[4];

    f32x16 acc[2];
#pragma unroll
    for (int j = 0; j < 2; ++j)
#pragma unroll
        for (int r = 0; r < 16; ++r) acc[j][r] = 0.f;

    // stage loads: 4 x float4; 16 consecutive lanes cover one 256B row chunk
#define SLOAD(ph)                                                            \
    do {                                                                     \
        _Pragma("unroll") for (int i_ = 0; i_ < 4; ++i_)                     \
            ld[i_] = *(const float4*)(xb + (size_t)(srow0 + i_ * 4) * P_ +   \
                                      (ph) * 64 + spx);                      \
    } while (0)

    // exact fp32 max/sum of the staged values, reduced over the 8-lane
    // 32-px block group, written wg-major (coalesced 4KB window per WG)
#define MSWRITE(ph)                                                          \
    do {                                                                     \
        _Pragma("unroll") for (int i_ = 0; i_ < 4; ++i_) {                   \
            float4 v_ = ld[i_];                                              \
            float m_ = fmaxf(fmaxf(v_.x, v_.y), fmaxf(v_.z, v_.w));          \
            float s_ = (v_.x + v_.y) + (v_.z + v_.w);                        \
            m_ = fmaxf(m_, __shfl_xor(m_, 1)); s_ += __shfl_xor(s_, 1);      \
            m_ = fmaxf(m_, __shfl_xor(m_, 2)); s_ += __shfl_xor(s_, 2);      \
            m_ = fmaxf(m_, __shfl_xor(m_, 4)); s_ += __shfl_xor(s_, 4);      \
            if ((l & 7) == 0) {                                              \
                int c_ = srow0 + i_ * 4;                                     \
                int j3_ = ((ph) & 3) * 2 + ((l >> 3) & 1);                   \
                size_t base_ = ((size_t)(wg * 2 + ((ph) >> 2)) * 128 + c_) * 8 + j3_; \
                ws[MAXP_OFF + base_] = m_;                                   \
                ws[SUMP_OFF + base_] = s_;                                   \
            }                                                                \
        }                                                                    \
    } while (0)

    // convert once + swizzled bf16 LDS store (8 B per lane per row)
#define SSTORE(ph)                                                           \
    do {                                                                     \
        _Pragma("unroll") for (int i_ = 0; i_ < 4; ++i_) {                   \
            int c_ = srow0 + i_ * 4;                                         \
            unsigned int u0_ = bfpair(ld[i_].x, ld[i_].y);                   \
            unsigned int u1_ = bfpair(ld[i_].z, ld[i_].w);                   \
            int ch_ = ((l & 15) >> 1) ^ (c_ & 7);                            \
            *(uint2*)((unsigned char*)buf[(ph) & 1] + c_ * 128 + (ch_ << 4) + \
                      (l & 1) * 8) = make_uint2(u0_, u1_);                   \
        }                                                                    \
    } while (0)

    // prologue: tile 0
    SLOAD(0);
    MSWRITE(0);
    SSTORE(0);
    __syncthreads();

#pragma unroll
    for (int ph = 0; ph < 8; ++ph) {
        if (ph < 7) SLOAD(ph + 1);  // issue early; hides under MFMA below
        const unsigned char* tl = (const unsigned char*)buf[ph & 1];
#pragma unroll
        for (int ks = 0; ks < 4; ++ks) {
            int rowa = qi * 32 + (l & 31);
            short8 fa = *(const short8*)(tl + rowa * 128 +
                ((((ks << 1) | (l >> 5)) ^ (rowa & 7)) << 4));
#pragma unroll
            for (int j = 0; j < 2; ++j) {
                int rowb = (qjb + j) * 32 + (l & 31);
                short8 fb = *(const short8*)(tl + rowb * 128 +
                    ((((ks << 1) | (l >> 5)) ^ (rowb & 7)) << 4));
                acc[j] = __builtin_amdgcn_mfma_f32_32x32x16_bf16(fa, fb, acc[j], 0, 0, 0);
            }
        }
        if (ph < 7) {
            MSWRITE(ph + 1);  // vmcnt waits land here (late)
            SSTORE(ph + 1);   // writes the OTHER buffer
        }
        __syncthreads();
    }
#undef SLOAD
#undef MSWRITE
#undef SSTORE

    // ---- write Gram partials [wg][128][128] (G symmetric -> layout-safe) ----
    size_t gb = (size_t)wg * 16384;
#pragma unroll
    for (int j = 0; j < 2; ++j)
#pragma unroll
        for (int r = 0; r < 16; ++r) {
            int row = qi * 32 + (r & 3) + 8 * (r >> 2) + 4 * (l >> 5);
            int col = (qjb + j) * 32 + (l & 31);
            gpart[gb + (size_t)row * 128 + col] = acc[j][r];
        }
}

// K2a: reduce Gram partials over 128 row-chunks per b. grid = 256, block 256
__global__ __launch_bounds__(256) void k_reduceG(const float* __restrict__ gpart,
                                                 float* __restrict__ ws) {
    int tid = blockIdx.x * 256 + threadIdx.x;  // 65536
    int b = tid >> 14, inner = tid & 16383;
    const float* p = gpart + (size_t)b * 128 * 16384 + inner;
    float s = 0.f;
    for (int r = 0; r < 128; ++r) s += p[(size_t)r * 16384];
    ws[G_OFF + tid] = s;
}

// K2b: reduce max/sum partials -> M3/S3/SX + pyramid. grid = 512 (bc=b*128+c),
// block 256: thread (blk = i3*8+j3, q) reduces 16 row-pairs x 2 halves.
__global__ __launch_bounds__(256) void k_reduceMS(float* __restrict__ ws) {
    int bc = blockIdx.x;  // 512
    int b = bc >> 7, c = bc & 127;
    int t = threadIdx.x;
    int blk = t >> 2, q = t & 3;
    int i3 = blk >> 3, j3 = blk & 7;
    __shared__ float bm[64], bs[64];
    __shared__ float lv[24];
    __shared__ float sxr[8];
    {
        float m = -FLT_MAX, s = 0.f;
        for (int rl = q; rl < 16; rl += 4) {
            int wg = b * 128 + i3 * 16 + rl;
            size_t base = (size_t)(wg * 2) * 1024 + (size_t)c * 8 + j3;
            m = fmaxf(m, ws[MAXP_OFF + base]);
            s += ws[SUMP_OFF + base];
            m = fmaxf(m, ws[MAXP_OFF + base + 1024]);
            s += ws[SUMP_OFF + base + 1024];
        }
        m = fmaxf(m, __shfl_xor(m, 1)); s += __shfl_xor(s, 1);
        m = fmaxf(m, __shfl_xor(m, 2)); s += __shfl_xor(s, 2);
        if (q == 0) {
            bm[blk] = m;
            bs[blk] = s;
            ws[M3_OFF + (size_t)bc * 64 + blk] = m;
            ws[S3_OFF + (size_t)bc * 64 + blk] = s;
        }
    }
    __syncthreads();
    if (t < 8) {
        float sx = 0.f;
        for (int r = 0; r < 8; ++r) sx += bs[t * 8 + r];
        sxr[t] = sx;
    }
    if (t < 16) {
        int i2 = t >> 2, j2 = t & 3;
        float m = -FLT_MAX;
        for (int a = 0; a < 2; ++a)
            for (int b2 = 0; b2 < 2; ++b2)
                m = fmaxf(m, bm[(2 * i2 + a) * 8 + 2 * j2 + b2]);
        lv[t] = m;
        ws[M2_OFF + (size_t)bc * 16 + t] = m;
    }
    __syncthreads();
    if (t == 0) {
        float sx = 0.f;
        for (int r = 0; r < 8; ++r) sx += sxr[r];
        ws[SX_OFF + bc] = sx;
    }
    if (t < 4) {
        int i1 = t >> 1, j1 = t & 1;
        float m = -FLT_MAX;
        for (int a = 0; a < 2; ++a)
            for (int b2 = 0; b2 < 2; ++b2)
                m = fmaxf(m, lv[(2 * i1 + a) * 4 + 2 * j1 + b2]);
        lv[16 + t] = m;
        ws[M1_OFF + (size_t)bc * 4 + t] = m;
    }
    __syncthreads();
    if (t == 0)
        ws[M0_OFF + bc] = fmaxf(fmaxf(lv[16], lv[17]), fmaxf(lv[18], lv[19]));
}

// K3a: y_d[b,co,blk] = sum_ci M_d[b,ci,blk] * conv_w[d][co][ci]
__global__ __launch_bounds__(256) void k_conv_pool(const float* __restrict__ conv_w,
                                                   float* __restrict__ ws) {
    int bid = blockIdx.x;
    int d = bid >> 4, b = (bid >> 2) & 3, cchunk = bid & 3;
    int NB = 1 << (2 * d);
    int rel = level_rel(d);
    const float* Mb = ws + rel + (size_t)b * 128 * NB;
    float* Yb = ws + YBASE_ + rel + (size_t)b * 128 * NB;
    __shared__ float mlds[8192];
    int t = threadIdx.x;
    int tot = 128 * NB;
    for (int i = t; i < tot; i += 256) mlds[i] = Mb[i];
    __syncthreads();
    if (NB >= 4) {
        int nbq = NB >> 2;
        int nq = 32 * nbq;
        for (int qi = t; qi < nq; qi += 256) {
            int co = cchunk * 32 + (qi >> (2 * d - 2));
            int bq = qi & (nbq - 1);
            const float* wrow = conv_w + ((size_t)d * 128 + co) * 128;
            float a0 = 0.f, a1 = 0.f, a2 = 0.f, a3 = 0.f;
            for (int ci = 0; ci < 128; ++ci) {
                float4 mv = *(const float4*)(&mlds[ci * NB + bq * 4]);
                float wvv = wrow[ci];
                a0 = fmaf(wvv, mv.x, a0);
                a1 = fmaf(wvv, mv.y, a1);
                a2 = fmaf(wvv, mv.z, a2);
                a3 = fmaf(wvv, mv.w, a3);
            }
            float4 r;
            r.x = a0; r.y = a1; r.z = a2; r.w = a3;
            *(float4*)(&Yb[co * NB + bq * 4]) = r;
        }
    } else {
        for (int oi = t; oi < 32; oi += 256) {
            int co = cchunk * 32 + oi;
            const float* wrow = conv_w + (size_t)co * 128;
            float acc = 0.f;
            for (int ci = 0; ci < 128; ++ci) acc = fmaf(mlds[ci], wrow[ci], acc);
            Yb[co] = acc;
        }
    }
}

// K3b: per-(d,c) BN stats
__global__ __launch_bounds__(256) void k_bnstats_d(const float* __restrict__ conv_g,
                                                   const float* __restrict__ conv_b,
                                                   float* __restrict__ ws) {
    int tid = blockIdx.x * 256 + threadIdx.x;
    if (tid >= 512) return;
    int d = tid >> 7, c = tid & 127;
    int NB = 1 << (2 * d);
    const float* Y = ws + YBASE_ + level_rel(d);
    int n = 4 * NB;
    float s = 0.f;
    for (int b = 0; b < 4; ++b)
        for (int k = 0; k < NB; ++k) s += Y[((size_t)b * 128 + c) * NB + k];
    float mean = s / (float)n;
    float v = 0.f;
    for (int b = 0; b < 4; ++b)
        for (int k = 0; k < NB; ++k) {
            float dd = Y[((size_t)b * 128 + c) * NB + k] - mean;
            v = fmaf(dd, dd, v);
        }
    float var = v / (float)n;
    float sc = conv_g[d * 128 + c] * rsqrtf(var + 1e-5f);
    ws[SCALED_OFF + tid] = sc;
    ws[SHIFTD_OFF + tid] = conv_b[d * 128 + c] - mean * sc;
}

// K3c: contrib[b][o][blk3]. grid = B*64, block 128 (thread = o)
__global__ __launch_bounds__(128) void k_contrib(const float* __restrict__ final_w,
                                                 float* __restrict__ ws) {
    int b = blockIdx.x >> 6, blk3 = blockIdx.x & 63;
    int i3 = blk3 >> 3, j3 = blk3 & 7;
    __shared__ float pn[512];
    int t = threadIdx.x;
    for (int k = t; k < 512; k += 128) {
        int d = k >> 7, c = k & 127;
        int sh = 3 - d;
        int blkd = (i3 >> sh) * (1 << d) + (j3 >> sh);
        int NB = 1 << (2 * d);
        float yv = ws[YBASE_ + level_rel(d) + ((size_t)b * 128 + c) * NB + blkd];
        pn[k] = yv * ws[SCALED_OFF + k] + ws[SHIFTD_OFF + k];
    }
    __syncthreads();
    const float* fw = final_w + (size_t)t * 640 + 128;
    float acc = 0.f;
#pragma unroll 8
    for (int k = 0; k < 512; k += 4) {
        float4 f = *(const float4*)(fw + k);
        acc = fmaf(pn[k], f.x, acc);
        acc = fmaf(pn[k + 1], f.y, acc);
        acc = fmaf(pn[k + 2], f.z, acc);
        acc = fmaf(pn[k + 3], f.w, acc);
    }
    ws[CONTRIB_OFF + ((size_t)b * 128 + t) * 64 + blk3] = acc;
}

// K4: closed-form final BN stats: sum(z^2) = wGw + 2*sum_blk cv*(w.S3) + 1024*sum cv^2
// grid = 128 (o), block 128 (t = c)
__global__ __launch_bounds__(128) void k_stats(const float* __restrict__ final_w,
                                               const float* __restrict__ final_g,
                                               const float* __restrict__ final_b,
                                               float* __restrict__ ws) {
    int o = blockIdx.x, t = threadIdx.x;
    __shared__ __align__(16) float wlds[128];
    __shared__ __align__(16) float cvl[64];
    __shared__ float rbuf[4];
    wlds[t] = final_w[(size_t)o * 640 + t];
    __syncthreads();
    float SSQ = 0.f, SUM = 0.f;
    for (int b = 0; b < 4; ++b) {
        if (t < 64) cvl[t] = ws[CONTRIB_OFF + (size_t)(b * 128 + o) * 64 + t];
        __syncthreads();
        const float* Gb = ws + G_OFF + (size_t)b * 16384 + (size_t)t * 128;
        float a1 = 0.f;
#pragma unroll 8
        for (int k = 0; k < 128; k += 4) {
            float4 g = *(const float4*)(Gb + k);
            float4 w = *(const float4*)(&wlds[k]);
            a1 = fmaf(g.x, w.x, fmaf(g.y, w.y, fmaf(g.z, w.z, fmaf(g.w, w.w, a1))));
        }
        const float* S3p = ws + S3_OFF + (size_t)(b * 128 + t) * 64;
        float a2 = 0.f;
#pragma unroll 8
        for (int k = 0; k < 64; k += 4) {
            float4 sv = *(const float4*)(S3p + k);
            float4 cv = *(const float4*)(&cvl[k]);
            a2 = fmaf(sv.x, cv.x, fmaf(sv.y, cv.y, fmaf(sv.z, cv.z, fmaf(sv.w, cv.w, a2))));
        }
        float r1 = (a1 + 2.f * a2) * wlds[t];
        float r2 = wlds[t] * ws[SX_OFF + b * 128 + t];
        if (t < 64) {
            r1 += 1024.f * cvl[t] * cvl[t];
            r2 += 1024.f * cvl[t];
        }
#pragma unroll
        for (int k = 1; k < 64; k <<= 1) {
            r1 += __shfl_xor(r1, k);
            r2 += __shfl_xor(r2, k);
        }
        if ((t & 63) == 0) {
            rbuf[(t >> 6) * 2] = r1;
            rbuf[(t >> 6) * 2 + 1] = r2;
        }
        __syncthreads();
        SSQ += rbuf[0] + rbuf[2];
        SUM += rbuf[1] + rbuf[3];
        __syncthreads();
    }
    if (t == 0) {
        float mean = SUM / 262144.f;
        float var = SSQ / 262144.f - mean * mean;
        float sc = final_g[o] * rsqrtf(var + 1e-5f);
        ws[SCALEF_OFF + o] = sc;
        ws[SHIFTF_OFF + o] = final_b[o] - mean * sc;
    }
}

// K5: out[b,o,p] = (MFMA(W0,x) + contrib) * scale[o] + shift[o].
// grid = 2048 (b*512 + ptile of 128), block 256 (4 waves; wave = 32 p)
__global__ __launch_bounds__(256) void k_out(const float* __restrict__ x,
                                             const float* __restrict__ final_w,
                                             const float* __restrict__ ws,
                                             float* __restrict__ out) {
    __shared__ uint4 wtileq[2048];  // [128 o][128 c] bf16, swizzled, 32KB
    __shared__ float scl[128], shf[128], cvs[512];
    unsigned char* wtile = (unsigned char*)wtileq;
    int wgid = blockIdx.x;
    int b = wgid >> 9, pt = wgid & 511;
    int p0 = pt * 128;
    int t = threadIdx.x, l = t & 63, wv = t >> 6;
#pragma unroll
    for (int it = 0; it < 32; ++it) {
        int pid = it * 256 + t;  // 8192 pairs
        int o = pid >> 6, cp = (pid & 63) * 2;
        float2 f = *(const float2*)(final_w + (size_t)o * 640 + cp);
        unsigned int u = bfpair(f.x, f.y);
        int wa = (o * 256 + cp * 2) ^ ((o & 7) << 4);
        *(unsigned int*)(wtile + wa) = u;
    }
    if (t < 128) {
        scl[t] = ws[SCALEF_OFF + t];
        shf[t] = ws[SHIFTF_OFF + t];
    }
    int i3 = pt >> 6, jb = (pt & 1) * 4;
    for (int q = t; q < 512; q += 256) {
        int o = q >> 2, jj = q & 3;
        cvs[q] = ws[CONTRIB_OFF + (size_t)(b * 128 + o) * 64 + i3 * 8 + jb + jj];
    }
    __syncthreads();

    const float* xb = x + (size_t)b * C_ * P_;
    int pw = p0 + wv * 32;
    f32x4 acc[8][2];
#pragma unroll
    for (int i = 0; i < 8; ++i) {
        acc[i][0] = (f32x4){0.f, 0.f, 0.f, 0.f};
        acc[i][1] = (f32x4){0.f, 0.f, 0.f, 0.f};
    }
#pragma unroll
    for (int ks = 0; ks < 4; ++ks) {
        short8 bf[2];
#pragma unroll
        for (int nt = 0; nt < 2; ++nt) {
            const float* xp = xb + (size_t)(ks * 32 + (l >> 4) * 8) * P_ + (pw + nt * 16 + (l & 15));
            float f0 = xp[0 * P_], f1 = xp[1 * P_], f2 = xp[2 * P_], f3 = xp[3 * P_];
            float f4 = xp[4 * P_], f5 = xp[5 * P_], f6 = xp[6 * P_], f7 = xp[7 * P_];
            union { uint4 u; short8 s; } cvtu;
            cvtu.u = make_uint4(bfpair(f0, f1), bfpair(f2, f3), bfpair(f4, f5), bfpair(f6, f7));
            bf[nt] = cvtu.s;
        }
#pragma unroll
        for (int mt = 0; mt < 8; ++mt) {
            int ra = ((mt * 16 + (l & 15)) * 256 + ks * 64 + (l >> 4) * 16) ^ ((l & 7) << 4);
            short8 af = *(const short8*)(wtile + ra);
            acc[mt][0] = __builtin_amdgcn_mfma_f32_16x16x32_bf16(af, bf[0], acc[mt][0], 0, 0, 0);
            acc[mt][1] = __builtin_amdgcn_mfma_f32_16x16x32_bf16(af, bf[1], acc[mt][1], 0, 0, 0);
        }
    }
#pragma unroll
    for (int mt = 0; mt < 8; ++mt)
#pragma unroll
        for (int nt = 0; nt < 2; ++nt) {
            int p = pw + nt * 16 + (l & 15);
            int jj = ((p & 255) >> 5) & 3;
#pragma unroll
            for (int r = 0; r < 4; ++r) {
                int o = mt * 16 + (l >> 4) * 4 + r;
                float z = acc[mt][nt][r] + cvs[o * 4 + jj];
                out[(size_t)(b * 128 + o) * P_ + p] = fmaf(z, scl[o], shf[o]);
            }
        }
}

extern "C" void kernel_launch(void* const* d_in, const int* in_sizes, int n_in,
                              void* d_out, int out_size, void* d_ws, size_t ws_size,
                              hipStream_t stream) {
    const float* x = (const float*)d_in[0];
    const float* conv_w = (const float*)d_in[1];
    const float* conv_g = (const float*)d_in[2];
    const float* conv_b = (const float*)d_in[3];
    const float* final_w = (const float*)d_in[4];
    const float* final_g = (const float*)d_in[5];
    const float* final_b = (const float*)d_in[6];
    float* out = (float*)d_out;
    float* ws = (float*)d_ws;

    // single fused pass over x: fp32-exact block max/sum partials + bf16 Gram
    // (Gram partials live in d_out scratch until k_reduceG; k_out overwrites d_out)
    k_gram_pool<<<512, 512, 0, stream>>>(x, ws, out);
    k_reduceG<<<256, 256, 0, stream>>>(out, ws);
    k_reduceMS<<<512, 256, 0, stream>>>(ws);
    k_conv_pool<<<64, 256, 0, stream>>>(conv_w, ws);
    k_bnstats_d<<<2, 256, 0, stream>>>(conv_g, conv_b, ws);
    k_contrib<<<B_ * 64, 128, 0, stream>>>(final_w, ws);
    k_stats<<<128, 128, 0, stream>>>(final_w, final_g, final_b, ws);
    k_out<<<2048, 256, 0, stream>>>(x, final_w, ws, out);
}

// Round 15
// 191.431 us; speedup vs baseline: 1.3597x; 1.0445x over previous
//
#include <hip/hip_runtime.h>
#include <hip/hip_bf16.h>
#include <math.h>
#include <float.h>

// x: [4,128,256,256] f32; conv_w: [4,128,128]; conv_g/b: [4,128]
// final_w: [128,640]; final_g/b: [128]; out: [4,128,256,256] f32
#define B_ 4
#define C_ 128
#define P_ 65536

// ---- workspace float offsets ----
#define M3_OFF      0        // [512][64] block maxima (32x32), exact fp32
#define M2_OFF      32768    // [512][16]
#define M1_OFF      40960    // [512][4]
#define M0_OFF      43008    // [512]
#define YBASE_      43520    // y levels, same internal layout as M
#define SCALED_OFF  87040    // [4][128]
#define SHIFTD_OFF  87552    // [4][128]
#define CONTRIB_OFF 88064    // [4][128][64]
#define S3_OFF      120832   // [512][64] block sums (32x32), exact fp32
#define SX_OFF      153600   // [512] per-(b,c) total sum
#define G_OFF       154112   // [4][128][128] Gram (bf16-sourced, fp32 accum)
#define SCALEF_OFF  219648   // [128]
#define SHIFTF_OFF  219776   // [128]
#define MAXP_OFF    219904   // [512 wg][4 qi][8 jc][32 l] = 524288 floats
#define SUMP_OFF    744192   // same layout, 524288 floats (FIXED: was overlapping MAXP)
// total floats: 1268480 (~4.84 MB)

using short8 = __attribute__((ext_vector_type(8))) short;
using f32x4 = __attribute__((ext_vector_type(4))) float;
using f32x16 = __attribute__((ext_vector_type(16))) float;

__device__ __forceinline__ int level_rel(int d) {
    return YBASE_ - 512 * (((1 << (2 * (d + 1))) - 1) / 3);
}

// RNE pack of two f32 into bf16x2 (low = first arg) — hardware v_cvt_pk_bf16_f32
__device__ __forceinline__ unsigned int bfpair(float a, float b) {
    union { __hip_bfloat162 h2; unsigned int u; } cv;
    cv.h2 = __float22bfloat162_rn(make_float2(a, b));
    return cv.u;
}

#define GLDS16(src, dst)                                                    \
    __builtin_amdgcn_global_load_lds(                                       \
        (const __attribute__((address_space(1))) unsigned int*)(src),       \
        (__attribute__((address_space(3))) unsigned int*)(dst), 16, 0, 0)

// K1: fused pass over x. 8 waves/WG (512 thr). 4-deep ring of [128 c][32 px]
// fp32 tiles staged via global_load_lds (slot-XOR swizzle on the global source;
// linear LDS dest). Counted s_waitcnt vmcnt(4) + raw s_barrier per phase keeps
// 2 future tiles in flight. Wave w computes G-quadrants (w&3, 2*(w>>2)+{0,1})
// via 32x32x16 MFMA with v_cvt_pk bf16 conversion; exact fp32 block max/sum
// folded into waves 0-3's A-side fragment loads (BEFORE rounding).
// grid = 512 (b*128 + rc; rc covers image rows 2rc, 2rc+1), block 512.
__global__ __launch_bounds__(512, 4) void k_gram_pool(const float* __restrict__ x,
                                                      float* __restrict__ ws,
                                                      float* __restrict__ gpart) {
    __shared__ float buf[4][4096];  // 4 x 16 KB; LDS[r][slot] = glob[r][slot ^ (r&7)]
    int wg = blockIdx.x;
    int b = wg >> 7, rc = wg & 127;
    const float* xb = x + (size_t)b * C_ * P_ + (size_t)rc * 512;
    int t_ = threadIdx.x, l = t_ & 63, wv = t_ >> 6;
    int qi = wv & 3;            // A quadrant-row
    int qjb = (wv >> 2) * 2;    // B quadrant-col base (2 quadrants per wave)
    bool doacc = (wv < 4);      // waves 0-3 own rows 32*qi..+32 max/sum
    int lrow = l >> 3, lch = l & 7;

    f32x16 acc[2];
#pragma unroll
    for (int j = 0; j < 2; ++j)
#pragma unroll
        for (int r = 0; r < 16; ++r) acc[j][r] = 0.f;
    float mxA[8], smA[8];  // per global 32-px col block
#pragma unroll
    for (int j = 0; j < 8; ++j) { mxA[j] = -FLT_MAX; smA[j] = 0.f; }

    // per-wave stage of tile tt: 2 gload_lds, each = 8 rows x 128 B
#define ISSUE(tt)                                                            \
    do {                                                                     \
        _Pragma("unroll") for (int i_ = 0; i_ < 2; ++i_) {                   \
            int row_ = wv * 16 + i_ * 8 + lrow;                              \
            int ch_ = lch ^ (row_ & 7);                                      \
            GLDS16(xb + (size_t)row_ * P_ + (tt) * 32 + ch_ * 4,             \
                   &buf[(tt) & 3][(wv * 16 + i_ * 8) * 32]);                 \
        }                                                                    \
    } while (0)

    // prologue: 3 tiles in flight (6 loads/wave outstanding)
    ISSUE(0);
    ISSUE(1);
    ISSUE(2);

#pragma unroll
    for (int t = 0; t < 16; ++t) {
        // drain ONLY tile t (oldest 2 loads); t+1,t+2 stay in flight
        if (t <= 13)
            asm volatile("s_waitcnt vmcnt(4)" ::: "memory");
        else if (t == 14)
            asm volatile("s_waitcnt vmcnt(2)" ::: "memory");
        else
            asm volatile("s_waitcnt vmcnt(0)" ::: "memory");
        __builtin_amdgcn_sched_barrier(0);
        __builtin_amdgcn_s_barrier();  // all waves' tile-t writes visible
        asm volatile("" ::: "memory");
        __builtin_amdgcn_sched_barrier(0);
        // tile t+3 overwrites buf[(t-1)&3]; its readers finished before this barrier
        if (t + 3 < 16) ISSUE(t + 3);

        const float* tl = &buf[t & 3][0];
        int jc = t & 7;  // global 32-px col block (compile-time under unroll)
#pragma unroll
        for (int ks = 0; ks < 2; ++ks) {
            int ch = ks * 4 + ((l >> 5) << 1);
            // A fragment (+ exact fp32 max/sum on waves 0-3)
            short8 fa;
            {
                int row = qi * 32 + (l & 31);
                int sw = row & 7;
                float4 v0 = *(const float4*)(tl + row * 32 + ((ch ^ sw) << 2));
                float4 v1 = *(const float4*)(tl + row * 32 + (((ch + 1) ^ sw) << 2));
                if (doacc) {
                    mxA[jc] = fmaxf(mxA[jc],
                        fmaxf(fmaxf(fmaxf(v0.x, v0.y), fmaxf(v0.z, v0.w)),
                              fmaxf(fmaxf(v1.x, v1.y), fmaxf(v1.z, v1.w))));
                    smA[jc] += ((v0.x + v0.y) + (v0.z + v0.w)) +
                               ((v1.x + v1.y) + (v1.z + v1.w));
                }
                union { uint4 u; short8 s8; } cu;
                cu.u = make_uint4(bfpair(v0.x, v0.y), bfpair(v0.z, v0.w),
                                  bfpair(v1.x, v1.y), bfpair(v1.z, v1.w));
                fa = cu.s8;
            }
#pragma unroll
            for (int j = 0; j < 2; ++j) {
                int row = (qjb + j) * 32 + (l & 31);
                int sw = row & 7;
                float4 v0 = *(const float4*)(tl + row * 32 + ((ch ^ sw) << 2));
                float4 v1 = *(const float4*)(tl + row * 32 + (((ch + 1) ^ sw) << 2));
                union { uint4 u; short8 s8; } cu;
                cu.u = make_uint4(bfpair(v0.x, v0.y), bfpair(v0.z, v0.w),
                                  bfpair(v1.x, v1.y), bfpair(v1.z, v1.w));
                acc[j] = __builtin_amdgcn_mfma_f32_32x32x16_bf16(fa, cu.s8, acc[j], 0, 0, 0);
            }
        }
    }
#undef ISSUE

    // ---- write Gram partials [wg][128][128] (G symmetric -> layout-safe) ----
    size_t gb = (size_t)wg * 16384;
#pragma unroll
    for (int j = 0; j < 2; ++j)
#pragma unroll
        for (int r = 0; r < 16; ++r) {
            int row = qi * 32 + (r & 3) + 8 * (r >> 2) + 4 * (l >> 5);
            int col = (qjb + j) * 32 + (l & 31);
            gpart[gb + (size_t)row * 128 + col] = acc[j][r];
        }
    // ---- max/sum epilogue: merge lane-halves, write wg-major coalesced ----
    if (doacc) {
#pragma unroll
        for (int jc = 0; jc < 8; ++jc) {
            float m = mxA[jc], sv = smA[jc];
            m = fmaxf(m, __shfl_xor(m, 32));
            sv += __shfl_xor(sv, 32);
            if (l < 32) {
                size_t idx = (size_t)wg * 1024 + qi * 256 + jc * 32 + l;
                ws[MAXP_OFF + idx] = m;   // 32 lanes -> 128 B contiguous
                ws[SUMP_OFF + idx] = sv;
            }
        }
    }
}

// K2a: reduce Gram partials over 128 row-chunks per b. grid = 256, block 256
__global__ __launch_bounds__(256) void k_reduceG(const float* __restrict__ gpart,
                                                 float* __restrict__ ws) {
    int tid = blockIdx.x * 256 + threadIdx.x;  // 65536
    int b = tid >> 14, inner = tid & 16383;
    const float* p = gpart + (size_t)b * 128 * 16384 + inner;
    float s = 0.f;
    for (int r = 0; r < 128; ++r) s += p[(size_t)r * 16384];
    ws[G_OFF + tid] = s;
}

// K2b: reduce max/sum partials -> M3/S3. grid = 256 (b*64 + i3*8 + g), block 128.
// Reads are contiguous 512B runs within each wg-slice (coalesced).
__global__ __launch_bounds__(128) void k_reduceMS3(float* __restrict__ ws) {
    int bid = blockIdx.x;
    int g = bid & 7, i3 = (bid >> 3) & 7, b = bid >> 6;
    int t = threadIdx.x;
    int cell = g * 128 + t;  // [qi][jc][l] linear index within a wg-slice
    float m = -FLT_MAX, s = 0.f;
#pragma unroll
    for (int rr = 0; rr < 16; ++rr) {
        size_t base = (size_t)(b * 128 + i3 * 16 + rr) * 1024 + cell;
        m = fmaxf(m, ws[MAXP_OFF + base]);
        s += ws[SUMP_OFF + base];
    }
    int c = ((cell >> 8) << 5) + (cell & 31);
    int jc = (cell >> 5) & 7;
    size_t o = (size_t)(b * 128 + c) * 64 + i3 * 8 + jc;
    ws[M3_OFF + o] = m;
    ws[S3_OFF + o] = s;
}

// K2c: pyramid M2/M1/M0 + SX from M3/S3. grid = 512 (bc), block 64 (one wave).
__global__ __launch_bounds__(64) void k_pyramid(float* __restrict__ ws) {
    int bc = blockIdx.x;
    int t = threadIdx.x;  // 0..63 = blk
    __shared__ float bm[64];
    __shared__ float lv[20];
    float m3 = ws[M3_OFF + (size_t)bc * 64 + t];
    float s3 = ws[S3_OFF + (size_t)bc * 64 + t];
    bm[t] = m3;
    float s = s3;
#pragma unroll
    for (int k = 1; k < 64; k <<= 1) s += __shfl_xor(s, k);
    if (t == 0) ws[SX_OFF + bc] = s;
    __syncthreads();
    if (t < 16) {
        int i2 = t >> 2, j2 = t & 3;
        float m = -FLT_MAX;
        for (int a = 0; a < 2; ++a)
            for (int b2 = 0; b2 < 2; ++b2)
                m = fmaxf(m, bm[(2 * i2 + a) * 8 + 2 * j2 + b2]);
        lv[t] = m;
        ws[M2_OFF + (size_t)bc * 16 + t] = m;
    }
    __syncthreads();
    if (t < 4) {
        int i1 = t >> 1, j1 = t & 1;
        float m = -FLT_MAX;
        for (int a = 0; a < 2; ++a)
            for (int b2 = 0; b2 < 2; ++b2)
                m = fmaxf(m, lv[(2 * i1 + a) * 4 + 2 * j1 + b2]);
        lv[16 + t] = m;
        ws[M1_OFF + (size_t)bc * 4 + t] = m;
    }
    __syncthreads();
    if (t == 0)
        ws[M0_OFF + bc] = fmaxf(fmaxf(lv[16], lv[17]), fmaxf(lv[18], lv[19]));
}

// K3a: y_d[b,co,blk] = sum_ci M_d[b,ci,blk] * conv_w[d][co][ci]
__global__ __launch_bounds__(256) void k_conv_pool(const float* __restrict__ conv_w,
                                                   float* __restrict__ ws) {
    int bid = blockIdx.x;
    int d = bid >> 4, b = (bid >> 2) & 3, cchunk = bid & 3;
    int NB = 1 << (2 * d);
    int rel = level_rel(d);
    const float* Mb = ws + rel + (size_t)b * 128 * NB;
    float* Yb = ws + YBASE_ + rel + (size_t)b * 128 * NB;
    __shared__ float mlds[8192];
    int t = threadIdx.x;
    int tot = 128 * NB;
    for (int i = t; i < tot; i += 256) mlds[i] = Mb[i];
    __syncthreads();
    if (NB >= 4) {
        int nbq = NB >> 2;
        int nq = 32 * nbq;
        for (int qi = t; qi < nq; qi += 256) {
            int co = cchunk * 32 + (qi >> (2 * d - 2));
            int bq = qi & (nbq - 1);
            const float* wrow = conv_w + ((size_t)d * 128 + co) * 128;
            float a0 = 0.f, a1 = 0.f, a2 = 0.f, a3 = 0.f;
            for (int ci = 0; ci < 128; ++ci) {
                float4 mv = *(const float4*)(&mlds[ci * NB + bq * 4]);
                float wvv = wrow[ci];
                a0 = fmaf(wvv, mv.x, a0);
                a1 = fmaf(wvv, mv.y, a1);
                a2 = fmaf(wvv, mv.z, a2);
                a3 = fmaf(wvv, mv.w, a3);
            }
            float4 r;
            r.x = a0; r.y = a1; r.z = a2; r.w = a3;
            *(float4*)(&Yb[co * NB + bq * 4]) = r;
        }
    } else {
        for (int oi = t; oi < 32; oi += 256) {
            int co = cchunk * 32 + oi;
            const float* wrow = conv_w + (size_t)co * 128;
            float acc = 0.f;
            for (int ci = 0; ci < 128; ++ci) acc = fmaf(mlds[ci], wrow[ci], acc);
            Yb[co] = acc;
        }
    }
}

// K3b: per-(d,c) BN stats
__global__ __launch_bounds__(256) void k_bnstats_d(const float* __restrict__ conv_g,
                                                   const float* __restrict__ conv_b,
                                                   float* __restrict__ ws) {
    int tid = blockIdx.x * 256 + threadIdx.x;
    if (tid >= 512) return;
    int d = tid >> 7, c = tid & 127;
    int NB = 1 << (2 * d);
    const float* Y = ws + YBASE_ + level_rel(d);
    int n = 4 * NB;
    float s = 0.f;
    for (int b = 0; b < 4; ++b)
        for (int k = 0; k < NB; ++k) s += Y[((size_t)b * 128 + c) * NB + k];
    float mean = s / (float)n;
    float v = 0.f;
    for (int b = 0; b < 4; ++b)
        for (int k = 0; k < NB; ++k) {
            float dd = Y[((size_t)b * 128 + c) * NB + k] - mean;
            v = fmaf(dd, dd, v);
        }
    float var = v / (float)n;
    float sc = conv_g[d * 128 + c] * rsqrtf(var + 1e-5f);
    ws[SCALED_OFF + tid] = sc;
    ws[SHIFTD_OFF + tid] = conv_b[d * 128 + c] - mean * sc;
}

// K3c: contrib[b][o][blk3]. grid = B*64, block 128 (thread = o)
__global__ __launch_bounds__(128) void k_contrib(const float* __restrict__ final_w,
                                                 float* __restrict__ ws) {
    int b = blockIdx.x >> 6, blk3 = blockIdx.x & 63;
    int i3 = blk3 >> 3, j3 = blk3 & 7;
    __shared__ float pn[512];
    int t = threadIdx.x;
    for (int k = t; k < 512; k += 128) {
        int d = k >> 7, c = k & 127;
        int sh = 3 - d;
        int blkd = (i3 >> sh) * (1 << d) + (j3 >> sh);
        int NB = 1 << (2 * d);
        float yv = ws[YBASE_ + level_rel(d) + ((size_t)b * 128 + c) * NB + blkd];
        pn[k] = yv * ws[SCALED_OFF + k] + ws[SHIFTD_OFF + k];
    }
    __syncthreads();
    const float* fw = final_w + (size_t)t * 640 + 128;
    float acc = 0.f;
#pragma unroll 8
    for (int k = 0; k < 512; k += 4) {
        float4 f = *(const float4*)(fw + k);
        acc = fmaf(pn[k], f.x, acc);
        acc = fmaf(pn[k + 1], f.y, acc);
        acc = fmaf(pn[k + 2], f.z, acc);
        acc = fmaf(pn[k + 3], f.w, acc);
    }
    ws[CONTRIB_OFF + ((size_t)b * 128 + t) * 64 + blk3] = acc;
}

// K4: closed-form final BN stats: sum(z^2) = wGw + 2*sum_blk cv*(w.S3) + 1024*sum cv^2
// grid = 128 (o), block 128 (t = c)
__global__ __launch_bounds__(128) void k_stats(const float* __restrict__ final_w,
                                               const float* __restrict__ final_g,
                                               const float* __restrict__ final_b,
                                               float* __restrict__ ws) {
    int o = blockIdx.x, t = threadIdx.x;
    __shared__ __align__(16) float wlds[128];
    __shared__ __align__(16) float cvl[64];
    __shared__ float rbuf[4];
    wlds[t] = final_w[(size_t)o * 640 + t];
    __syncthreads();
    float SSQ = 0.f, SUM = 0.f;
    for (int b = 0; b < 4; ++b) {
        if (t < 64) cvl[t] = ws[CONTRIB_OFF + (size_t)(b * 128 + o) * 64 + t];
        __syncthreads();
        const float* Gb = ws + G_OFF + (size_t)b * 16384 + (size_t)t * 128;
        float a1 = 0.f;
#pragma unroll 8
        for (int k = 0; k < 128; k += 4) {
            float4 g = *(const float4*)(Gb + k);
            float4 w = *(const float4*)(&wlds[k]);
            a1 = fmaf(g.x, w.x, fmaf(g.y, w.y, fmaf(g.z, w.z, fmaf(g.w, w.w, a1))));
        }
        const float* S3p = ws + S3_OFF + (size_t)(b * 128 + t) * 64;
        float a2 = 0.f;
#pragma unroll 8
        for (int k = 0; k < 64; k += 4) {
            float4 sv = *(const float4*)(S3p + k);
            float4 cv = *(const float4*)(&cvl[k]);
            a2 = fmaf(sv.x, cv.x, fmaf(sv.y, cv.y, fmaf(sv.z, cv.z, fmaf(sv.w, cv.w, a2))));
        }
        float r1 = (a1 + 2.f * a2) * wlds[t];
        float r2 = wlds[t] * ws[SX_OFF + b * 128 + t];
        if (t < 64) {
            r1 += 1024.f * cvl[t] * cvl[t];
            r2 += 1024.f * cvl[t];
        }
#pragma unroll
        for (int k = 1; k < 64; k <<= 1) {
            r1 += __shfl_xor(r1, k);
            r2 += __shfl_xor(r2, k);
        }
        if ((t & 63) == 0) {
            rbuf[(t >> 6) * 2] = r1;
            rbuf[(t >> 6) * 2 + 1] = r2;
        }
        __syncthreads();
        SSQ += rbuf[0] + rbuf[2];
        SUM += rbuf[1] + rbuf[3];
        __syncthreads();
    }
    if (t == 0) {
        float mean = SUM / 262144.f;
        float var = SSQ / 262144.f - mean * mean;
        float sc = final_g[o] * rsqrtf(var + 1e-5f);
        ws[SCALEF_OFF + o] = sc;
        ws[SHIFTF_OFF + o] = final_b[o] - mean * sc;
    }
}

// K5: out[b,o,p] = (MFMA(W0,x) + contrib) * scale[o] + shift[o].
// grid = 2048 (b*512 + ptile of 128), block 256 (4 waves; wave = 32 p)
__global__ __launch_bounds__(256) void k_out(const float* __restrict__ x,
                                             const float* __restrict__ final_w,
                                             const float* __restrict__ ws,
                                             float* __restrict__ out) {
    __shared__ uint4 wtileq[2048];  // [128 o][128 c] bf16, swizzled, 32KB
    __shared__ float scl[128], shf[128], cvs[512];
    unsigned char* wtile = (unsigned char*)wtileq;
    int wgid = blockIdx.x;
    int b = wgid >> 9, pt = wgid & 511;
    int p0 = pt * 128;
    int t = threadIdx.x, l = t & 63, wv = t >> 6;
#pragma unroll
    for (int it = 0; it < 32; ++it) {
        int pid = it * 256 + t;  // 8192 pairs
        int o = pid >> 6, cp = (pid & 63) * 2;
        float2 f = *(const float2*)(final_w + (size_t)o * 640 + cp);
        unsigned int u = bfpair(f.x, f.y);
        int wa = (o * 256 + cp * 2) ^ ((o & 7) << 4);
        *(unsigned int*)(wtile + wa) = u;
    }
    if (t < 128) {
        scl[t] = ws[SCALEF_OFF + t];
        shf[t] = ws[SHIFTF_OFF + t];
    }
    int i3 = pt >> 6, jb = (pt & 1) * 4;
    for (int q = t; q < 512; q += 256) {
        int o = q >> 2, jj = q & 3;
        cvs[q] = ws[CONTRIB_OFF + (size_t)(b * 128 + o) * 64 + i3 * 8 + jb + jj];
    }
    __syncthreads();

    const float* xb = x + (size_t)b * C_ * P_;
    int pw = p0 + wv * 32;
    f32x4 acc[8][2];
#pragma unroll
    for (int i = 0; i < 8; ++i) {
        acc[i][0] = (f32x4){0.f, 0.f, 0.f, 0.f};
        acc[i][1] = (f32x4){0.f, 0.f, 0.f, 0.f};
    }
#pragma unroll
    for (int ks = 0; ks < 4; ++ks) {
        short8 bf[2];
#pragma unroll
        for (int nt = 0; nt < 2; ++nt) {
            const float* xp = xb + (size_t)(ks * 32 + (l >> 4) * 8) * P_ + (pw + nt * 16 + (l & 15));
            float f0 = xp[0 * P_], f1 = xp[1 * P_], f2 = xp[2 * P_], f3 = xp[3 * P_];
            float f4 = xp[4 * P_], f5 = xp[5 * P_], f6 = xp[6 * P_], f7 = xp[7 * P_];
            union { uint4 u; short8 s; } cvtu;
            cvtu.u = make_uint4(bfpair(f0, f1), bfpair(f2, f3), bfpair(f4, f5), bfpair(f6, f7));
            bf[nt] = cvtu.s;
        }
#pragma unroll
        for (int mt = 0; mt < 8; ++mt) {
            int ra = ((mt * 16 + (l & 15)) * 256 + ks * 64 + (l >> 4) * 16) ^ ((l & 7) << 4);
            short8 af = *(const short8*)(wtile + ra);
            acc[mt][0] = __builtin_amdgcn_mfma_f32_16x16x32_bf16(af, bf[0], acc[mt][0], 0, 0, 0);
            acc[mt][1] = __builtin_amdgcn_mfma_f32_16x16x32_bf16(af, bf[1], acc[mt][1], 0, 0, 0);
        }
    }
#pragma unroll
    for (int mt = 0; mt < 8; ++mt)
#pragma unroll
        for (int nt = 0; nt < 2; ++nt) {
            int p = pw + nt * 16 + (l & 15);
            int jj = ((p & 255) >> 5) & 3;
#pragma unroll
            for (int r = 0; r < 4; ++r) {
                int o = mt * 16 + (l >> 4) * 4 + r;
                float z = acc[mt][nt][r] + cvs[o * 4 + jj];
                out[(size_t)(b * 128 + o) * P_ + p] = fmaf(z, scl[o], shf[o]);
            }
        }
}

extern "C" void kernel_launch(void* const* d_in, const int* in_sizes, int n_in,
                              void* d_out, int out_size, void* d_ws, size_t ws_size,
                              hipStream_t stream) {
    const float* x = (const float*)d_in[0];
    const float* conv_w = (const float*)d_in[1];
    const float* conv_g = (const float*)d_in[2];
    const float* conv_b = (const float*)d_in[3];
    const float* final_w = (const float*)d_in[4];
    const float* final_g = (const float*)d_in[5];
    const float* final_b = (const float*)d_in[6];
    float* out = (float*)d_out;
    float* ws = (float*)d_ws;

    // single fused pass over x: fp32-exact block max/sum partials + bf16 Gram
    // (Gram partials live in d_out scratch until k_reduceG; k_out overwrites d_out)
    k_gram_pool<<<512, 512, 0, stream>>>(x, ws, out);
    k_reduceG<<<256, 256, 0, stream>>>(out, ws);
    k_reduceMS3<<<256, 128, 0, stream>>>(ws);
    k_pyramid<<<512, 64, 0, stream>>>(ws);
    k_conv_pool<<<64, 256, 0, stream>>>(conv_w, ws);
    k_bnstats_d<<<2, 256, 0, stream>>>(conv_g, conv_b, ws);
    k_contrib<<<B_ * 64, 128, 0, stream>>>(final_w, ws);
    k_stats<<<128, 128, 0, stream>>>(final_w, final_g, final_b, ws);
    k_out<<<2048, 256, 0, stream>>>(x, final_w, ws, out);
}

// Round 16
// 188.154 us; speedup vs baseline: 1.3834x; 1.0174x over previous
//
#include <hip/hip_runtime.h>
#include <hip/hip_bf16.h>
#include <math.h>
#include <float.h>

// x: [4,128,256,256] f32; conv_w: [4,128,128]; conv_g/b: [4,128]
// final_w: [128,640]; final_g/b: [128]; out: [4,128,256,256] f32
#define B_ 4
#define C_ 128
#define P_ 65536

// ---- workspace float offsets ----
#define M3_OFF      0        // [512][64] block maxima (32x32), exact fp32
#define M2_OFF      32768    // [512][16]
#define M1_OFF      40960    // [512][4]
#define M0_OFF      43008    // [512]
#define YBASE_      43520    // y levels, same internal layout as M
#define SCALED_OFF  87040    // [4][128]
#define SHIFTD_OFF  87552    // [4][128]
#define CONTRIB_OFF 88064    // [4][128][64]
#define S3_OFF      120832   // [512][64] block sums (32x32), exact fp32
#define SX_OFF      153600   // [512] per-(b,c) total sum
#define G_OFF       154112   // [4][128][128] Gram (bf16-sourced, fp32 accum)
#define SCALEF_OFF  219648   // [128]
#define SHIFTF_OFF  219776   // [128]
#define MAXP_OFF    219904   // [512 wg][4 qi][8 jc][32 l] = 524288 floats
#define SUMP_OFF    744192   // same layout, 524288 floats
// total floats: 1268480 (~4.84 MB)

using short8 = __attribute__((ext_vector_type(8))) short;
using f32x4 = __attribute__((ext_vector_type(4))) float;
using f32x16 = __attribute__((ext_vector_type(16))) float;

__device__ __forceinline__ int level_rel(int d) {
    return YBASE_ - 512 * (((1 << (2 * (d + 1))) - 1) / 3);
}

// RNE pack of two f32 into bf16x2 (low = first arg) — hardware v_cvt_pk_bf16_f32
__device__ __forceinline__ unsigned int bfpair(float a, float b) {
    union { __hip_bfloat162 h2; unsigned int u; } cv;
    cv.h2 = __float22bfloat162_rn(make_float2(a, b));
    return cv.u;
}

#define GLDS16(src, dst)                                                    \
    __builtin_amdgcn_global_load_lds(                                       \
        (const __attribute__((address_space(1))) unsigned int*)(src),       \
        (__attribute__((address_space(3))) unsigned int*)(dst), 16, 0, 0)

// K1: fused pass over x. 8 waves/WG (512 thr). 4-deep ring of [128 c][32 px]
// fp32 tiles staged via global_load_lds (slot-XOR swizzle on the global source;
// linear LDS dest). Counted s_waitcnt vmcnt(4) + raw s_barrier per phase keeps
// 2 future tiles in flight. Wave w computes G-quadrants (w&3, 2*(w>>2)+{0,1})
// via 32x32x16 MFMA with v_cvt_pk bf16 conversion; exact fp32 block max/sum
// folded into waves 0-3's A-side fragment loads (BEFORE rounding).
// Gram partials stored as bf16 pairs (rows 2k,2k+1 packed in one u32).
// grid = 512 (b*128 + rc; rc covers image rows 2rc, 2rc+1), block 512.
__global__ __launch_bounds__(512, 4) void k_gram_pool(const float* __restrict__ x,
                                                      float* __restrict__ ws,
                                                      unsigned int* __restrict__ gpart) {
    __shared__ float buf[4][4096];  // 4 x 16 KB; LDS[r][slot] = glob[r][slot ^ (r&7)]
    int wg = blockIdx.x;
    int b = wg >> 7, rc = wg & 127;
    const float* xb = x + (size_t)b * C_ * P_ + (size_t)rc * 512;
    int t_ = threadIdx.x, l = t_ & 63, wv = t_ >> 6;
    int qi = wv & 3;            // A quadrant-row
    int qjb = (wv >> 2) * 2;    // B quadrant-col base (2 quadrants per wave)
    bool doacc = (wv < 4);      // waves 0-3 own rows 32*qi..+32 max/sum
    int lrow = l >> 3, lch = l & 7;

    f32x16 acc[2];
#pragma unroll
    for (int j = 0; j < 2; ++j)
#pragma unroll
        for (int r = 0; r < 16; ++r) acc[j][r] = 0.f;
    float mxA[8], smA[8];  // per global 32-px col block
#pragma unroll
    for (int j = 0; j < 8; ++j) { mxA[j] = -FLT_MAX; smA[j] = 0.f; }

    // per-wave stage of tile tt: 2 gload_lds, each = 8 rows x 128 B
#define ISSUE(tt)                                                            \
    do {                                                                     \
        _Pragma("unroll") for (int i_ = 0; i_ < 2; ++i_) {                   \
            int row_ = wv * 16 + i_ * 8 + lrow;                              \
            int ch_ = lch ^ (row_ & 7);                                      \
            GLDS16(xb + (size_t)row_ * P_ + (tt) * 32 + ch_ * 4,             \
                   &buf[(tt) & 3][(wv * 16 + i_ * 8) * 32]);                 \
        }                                                                    \
    } while (0)

    // prologue: 3 tiles in flight (6 loads/wave outstanding)
    ISSUE(0);
    ISSUE(1);
    ISSUE(2);

#pragma unroll
    for (int t = 0; t < 16; ++t) {
        // drain ONLY tile t (oldest 2 loads); t+1,t+2 stay in flight
        if (t <= 13)
            asm volatile("s_waitcnt vmcnt(4)" ::: "memory");
        else if (t == 14)
            asm volatile("s_waitcnt vmcnt(2)" ::: "memory");
        else
            asm volatile("s_waitcnt vmcnt(0)" ::: "memory");
        __builtin_amdgcn_sched_barrier(0);
        __builtin_amdgcn_s_barrier();  // all waves' tile-t writes visible
        asm volatile("" ::: "memory");
        __builtin_amdgcn_sched_barrier(0);
        // tile t+3 overwrites buf[(t-1)&3]; its readers finished before this barrier
        if (t + 3 < 16) ISSUE(t + 3);

        const float* tl = &buf[t & 3][0];
        int jc = t & 7;  // global 32-px col block (compile-time under unroll)
#pragma unroll
        for (int ks = 0; ks < 2; ++ks) {
            int ch = ks * 4 + ((l >> 5) << 1);
            // A fragment (+ exact fp32 max/sum on waves 0-3)
            short8 fa;
            {
                int row = qi * 32 + (l & 31);
                int sw = row & 7;
                float4 v0 = *(const float4*)(tl + row * 32 + ((ch ^ sw) << 2));
                float4 v1 = *(const float4*)(tl + row * 32 + (((ch + 1) ^ sw) << 2));
                if (doacc) {
                    mxA[jc] = fmaxf(mxA[jc],
                        fmaxf(fmaxf(fmaxf(v0.x, v0.y), fmaxf(v0.z, v0.w)),
                              fmaxf(fmaxf(v1.x, v1.y), fmaxf(v1.z, v1.w))));
                    smA[jc] += ((v0.x + v0.y) + (v0.z + v0.w)) +
                               ((v1.x + v1.y) + (v1.z + v1.w));
                }
                union { uint4 u; short8 s8; } cu;
                cu.u = make_uint4(bfpair(v0.x, v0.y), bfpair(v0.z, v0.w),
                                  bfpair(v1.x, v1.y), bfpair(v1.z, v1.w));
                fa = cu.s8;
            }
#pragma unroll
            for (int j = 0; j < 2; ++j) {
                int row = (qjb + j) * 32 + (l & 31);
                int sw = row & 7;
                float4 v0 = *(const float4*)(tl + row * 32 + ((ch ^ sw) << 2));
                float4 v1 = *(const float4*)(tl + row * 32 + (((ch + 1) ^ sw) << 2));
                union { uint4 u; short8 s8; } cu;
                cu.u = make_uint4(bfpair(v0.x, v0.y), bfpair(v0.z, v0.w),
                                  bfpair(v1.x, v1.y), bfpair(v1.z, v1.w));
                acc[j] = __builtin_amdgcn_mfma_f32_32x32x16_bf16(fa, cu.s8, acc[j], 0, 0, 0);
            }
        }
    }
#undef ISSUE

    // ---- write Gram partials as bf16 pairs: [wg][64 rowpair][128 col] u32.
    // Rows for (r, r+1), r even, are consecutive (row map (r&3)+8*(r>>2));
    // all base terms even -> row>>1 is the rowpair index. G symmetric ->
    // row/col convention self-consistent.
    {
        size_t gb = (size_t)wg * 8192;
#pragma unroll
        for (int j = 0; j < 2; ++j)
#pragma unroll
            for (int r = 0; r < 8; ++r) {
                int r2 = 2 * r;
                int row = qi * 32 + (r2 & 3) + 8 * (r2 >> 2) + 4 * (l >> 5);
                int col = (qjb + j) * 32 + (l & 31);
                gpart[gb + (size_t)(row >> 1) * 128 + col] =
                    bfpair(acc[j][r2], acc[j][r2 + 1]);
            }
    }
    // ---- max/sum epilogue: merge lane-halves, write wg-major coalesced ----
    if (doacc) {
#pragma unroll
        for (int jc = 0; jc < 8; ++jc) {
            float m = mxA[jc], sv = smA[jc];
            m = fmaxf(m, __shfl_xor(m, 32));
            sv += __shfl_xor(sv, 32);
            if (l < 32) {
                size_t idx = (size_t)wg * 1024 + qi * 256 + jc * 32 + l;
                ws[MAXP_OFF + idx] = m;   // 32 lanes -> 128 B contiguous
                ws[SUMP_OFF + idx] = sv;
            }
        }
    }
}

// K2a: reduce bf16 Gram partials over 128 row-chunks per b. grid = 128, block 256.
// Each thread sums one (rowpair, col) cell across slices, writes both G rows.
__global__ __launch_bounds__(256) void k_reduceG(const unsigned int* __restrict__ gpart,
                                                 float* __restrict__ ws) {
    int tid = blockIdx.x * 256 + threadIdx.x;  // 32768
    int b = tid >> 13, inner = tid & 8191;     // rowpair*128 + col
    const unsigned int* p = gpart + (size_t)b * 128 * 8192 + inner;
    float slo = 0.f, shi = 0.f;
    for (int r = 0; r < 128; ++r) {
        unsigned int u = p[(size_t)r * 8192];
        slo += __uint_as_float(u << 16);
        shi += __uint_as_float(u & 0xffff0000u);
    }
    int rp = inner >> 7, col = inner & 127;
    ws[G_OFF + (size_t)b * 16384 + (size_t)(2 * rp) * 128 + col] = slo;
    ws[G_OFF + (size_t)b * 16384 + (size_t)(2 * rp + 1) * 128 + col] = shi;
}

// K2b: reduce max/sum partials -> M3/S3. grid = 256 (b*64 + i3*8 + g), block 128.
__global__ __launch_bounds__(128) void k_reduceMS3(float* __restrict__ ws) {
    int bid = blockIdx.x;
    int g = bid & 7, i3 = (bid >> 3) & 7, b = bid >> 6;
    int t = threadIdx.x;
    int cell = g * 128 + t;  // [qi][jc][l] linear index within a wg-slice
    float m = -FLT_MAX, s = 0.f;
#pragma unroll
    for (int rr = 0; rr < 16; ++rr) {
        size_t base = (size_t)(b * 128 + i3 * 16 + rr) * 1024 + cell;
        m = fmaxf(m, ws[MAXP_OFF + base]);
        s += ws[SUMP_OFF + base];
    }
    int c = ((cell >> 8) << 5) + (cell & 31);
    int jc = (cell >> 5) & 7;
    size_t o = (size_t)(b * 128 + c) * 64 + i3 * 8 + jc;
    ws[M3_OFF + o] = m;
    ws[S3_OFF + o] = s;
}

// K2c: pyramid M2/M1/M0 + SX from M3/S3. grid = 512 (bc), block 64 (one wave).
__global__ __launch_bounds__(64) void k_pyramid(float* __restrict__ ws) {
    int bc = blockIdx.x;
    int t = threadIdx.x;  // 0..63 = blk
    __shared__ float bm[64];
    __shared__ float lv[20];
    float m3 = ws[M3_OFF + (size_t)bc * 64 + t];
    float s3 = ws[S3_OFF + (size_t)bc * 64 + t];
    bm[t] = m3;
    float s = s3;
#pragma unroll
    for (int k = 1; k < 64; k <<= 1) s += __shfl_xor(s, k);
    if (t == 0) ws[SX_OFF + bc] = s;
    __syncthreads();
    if (t < 16) {
        int i2 = t >> 2, j2 = t & 3;
        float m = -FLT_MAX;
        for (int a = 0; a < 2; ++a)
            for (int b2 = 0; b2 < 2; ++b2)
                m = fmaxf(m, bm[(2 * i2 + a) * 8 + 2 * j2 + b2]);
        lv[t] = m;
        ws[M2_OFF + (size_t)bc * 16 + t] = m;
    }
    __syncthreads();
    if (t < 4) {
        int i1 = t >> 1, j1 = t & 1;
        float m = -FLT_MAX;
        for (int a = 0; a < 2; ++a)
            for (int b2 = 0; b2 < 2; ++b2)
                m = fmaxf(m, lv[(2 * i1 + a) * 4 + 2 * j1 + b2]);
        lv[16 + t] = m;
        ws[M1_OFF + (size_t)bc * 4 + t] = m;
    }
    __syncthreads();
    if (t == 0)
        ws[M0_OFF + bc] = fmaxf(fmaxf(lv[16], lv[17]), fmaxf(lv[18], lv[19]));
}

// K3a: y_d[b,co,blk] = sum_ci M_d[b,ci,blk] * conv_w[d][co][ci]
__global__ __launch_bounds__(256) void k_conv_pool(const float* __restrict__ conv_w,
                                                   float* __restrict__ ws) {
    int bid = blockIdx.x;
    int d = bid >> 4, b = (bid >> 2) & 3, cchunk = bid & 3;
    int NB = 1 << (2 * d);
    int rel = level_rel(d);
    const float* Mb = ws + rel + (size_t)b * 128 * NB;
    float* Yb = ws + YBASE_ + rel + (size_t)b * 128 * NB;
    __shared__ float mlds[8192];
    int t = threadIdx.x;
    int tot = 128 * NB;
    for (int i = t; i < tot; i += 256) mlds[i] = Mb[i];
    __syncthreads();
    if (NB >= 4) {
        int nbq = NB >> 2;
        int nq = 32 * nbq;
        for (int qi = t; qi < nq; qi += 256) {
            int co = cchunk * 32 + (qi >> (2 * d - 2));
            int bq = qi & (nbq - 1);
            const float* wrow = conv_w + ((size_t)d * 128 + co) * 128;
            float a0 = 0.f, a1 = 0.f, a2 = 0.f, a3 = 0.f;
            for (int ci = 0; ci < 128; ++ci) {
                float4 mv = *(const float4*)(&mlds[ci * NB + bq * 4]);
                float wvv = wrow[ci];
                a0 = fmaf(wvv, mv.x, a0);
                a1 = fmaf(wvv, mv.y, a1);
                a2 = fmaf(wvv, mv.z, a2);
                a3 = fmaf(wvv, mv.w, a3);
            }
            float4 r;
            r.x = a0; r.y = a1; r.z = a2; r.w = a3;
            *(float4*)(&Yb[co * NB + bq * 4]) = r;
        }
    } else {
        for (int oi = t; oi < 32; oi += 256) {
            int co = cchunk * 32 + oi;
            const float* wrow = conv_w + (size_t)co * 128;
            float acc = 0.f;
            for (int ci = 0; ci < 128; ++ci) acc = fmaf(mlds[ci], wrow[ci], acc);
            Yb[co] = acc;
        }
    }
}

// K3b: per-(d,c) BN stats
__global__ __launch_bounds__(256) void k_bnstats_d(const float* __restrict__ conv_g,
                                                   const float* __restrict__ conv_b,
                                                   float* __restrict__ ws) {
    int tid = blockIdx.x * 256 + threadIdx.x;
    if (tid >= 512) return;
    int d = tid >> 7, c = tid & 127;
    int NB = 1 << (2 * d);
    const float* Y = ws + YBASE_ + level_rel(d);
    int n = 4 * NB;
    float s = 0.f;
    for (int b = 0; b < 4; ++b)
        for (int k = 0; k < NB; ++k) s += Y[((size_t)b * 128 + c) * NB + k];
    float mean = s / (float)n;
    float v = 0.f;
    for (int b = 0; b < 4; ++b)
        for (int k = 0; k < NB; ++k) {
            float dd = Y[((size_t)b * 128 + c) * NB + k] - mean;
            v = fmaf(dd, dd, v);
        }
    float var = v / (float)n;
    float sc = conv_g[d * 128 + c] * rsqrtf(var + 1e-5f);
    ws[SCALED_OFF + tid] = sc;
    ws[SHIFTD_OFF + tid] = conv_b[d * 128 + c] - mean * sc;
}

// K3c: contrib[b][o][blk3]. grid = B*64, block 128 (thread = o)
__global__ __launch_bounds__(128) void k_contrib(const float* __restrict__ final_w,
                                                 float* __restrict__ ws) {
    int b = blockIdx.x >> 6, blk3 = blockIdx.x & 63;
    int i3 = blk3 >> 3, j3 = blk3 & 7;
    __shared__ float pn[512];
    int t = threadIdx.x;
    for (int k = t; k < 512; k += 128) {
        int d = k >> 7, c = k & 127;
        int sh = 3 - d;
        int blkd = (i3 >> sh) * (1 << d) + (j3 >> sh);
        int NB = 1 << (2 * d);
        float yv = ws[YBASE_ + level_rel(d) + ((size_t)b * 128 + c) * NB + blkd];
        pn[k] = yv * ws[SCALED_OFF + k] + ws[SHIFTD_OFF + k];
    }
    __syncthreads();
    const float* fw = final_w + (size_t)t * 640 + 128;
    float acc = 0.f;
#pragma unroll 8
    for (int k = 0; k < 512; k += 4) {
        float4 f = *(const float4*)(fw + k);
        acc = fmaf(pn[k], f.x, acc);
        acc = fmaf(pn[k + 1], f.y, acc);
        acc = fmaf(pn[k + 2], f.z, acc);
        acc = fmaf(pn[k + 3], f.w, acc);
    }
    ws[CONTRIB_OFF + ((size_t)b * 128 + t) * 64 + blk3] = acc;
}

// K4: closed-form final BN stats: sum(z^2) = wGw + 2*sum_blk cv*(w.S3) + 1024*sum cv^2
// grid = 128 (o), block 128 (t = c)
__global__ __launch_bounds__(128) void k_stats(const float* __restrict__ final_w,
                                               const float* __restrict__ final_g,
                                               const float* __restrict__ final_b,
                                               float* __restrict__ ws) {
    int o = blockIdx.x, t = threadIdx.x;
    __shared__ __align__(16) float wlds[128];
    __shared__ __align__(16) float cvl[64];
    __shared__ float rbuf[4];
    wlds[t] = final_w[(size_t)o * 640 + t];
    __syncthreads();
    float SSQ = 0.f, SUM = 0.f;
    for (int b = 0; b < 4; ++b) {
        if (t < 64) cvl[t] = ws[CONTRIB_OFF + (size_t)(b * 128 + o) * 64 + t];
        __syncthreads();
        const float* Gb = ws + G_OFF + (size_t)b * 16384 + (size_t)t * 128;
        float a1 = 0.f;
#pragma unroll 8
        for (int k = 0; k < 128; k += 4) {
            float4 g = *(const float4*)(Gb + k);
            float4 w = *(const float4*)(&wlds[k]);
            a1 = fmaf(g.x, w.x, fmaf(g.y, w.y, fmaf(g.z, w.z, fmaf(g.w, w.w, a1))));
        }
        const float* S3p = ws + S3_OFF + (size_t)(b * 128 + t) * 64;
        float a2 = 0.f;
#pragma unroll 8
        for (int k = 0; k < 64; k += 4) {
            float4 sv = *(const float4*)(S3p + k);
            float4 cv = *(const float4*)(&cvl[k]);
            a2 = fmaf(sv.x, cv.x, fmaf(sv.y, cv.y, fmaf(sv.z, cv.z, fmaf(sv.w, cv.w, a2))));
        }
        float r1 = (a1 + 2.f * a2) * wlds[t];
        float r2 = wlds[t] * ws[SX_OFF + b * 128 + t];
        if (t < 64) {
            r1 += 1024.f * cvl[t] * cvl[t];
            r2 += 1024.f * cvl[t];
        }
#pragma unroll
        for (int k = 1; k < 64; k <<= 1) {
            r1 += __shfl_xor(r1, k);
            r2 += __shfl_xor(r2, k);
        }
        if ((t & 63) == 0) {
            rbuf[(t >> 6) * 2] = r1;
            rbuf[(t >> 6) * 2 + 1] = r2;
        }
        __syncthreads();
        SSQ += rbuf[0] + rbuf[2];
        SUM += rbuf[1] + rbuf[3];
        __syncthreads();
    }
    if (t == 0) {
        float mean = SUM / 262144.f;
        float var = SSQ / 262144.f - mean * mean;
        float sc = final_g[o] * rsqrtf(var + 1e-5f);
        ws[SCALEF_OFF + o] = sc;
        ws[SHIFTF_OFF + o] = final_b[o] - mean * sc;
    }
}

// K5: out[b,o,p] = (MFMA(W0,x) + contrib) * scale[o] + shift[o].
// grid = 2048 (b*512 + ptile of 128), block 256 (4 waves; wave = 32 p)
__global__ __launch_bounds__(256) void k_out(const float* __restrict__ x,
                                             const float* __restrict__ final_w,
                                             const float* __restrict__ ws,
                                             float* __restrict__ out) {
    __shared__ uint4 wtileq[2048];  // [128 o][128 c] bf16, swizzled, 32KB
    __shared__ float scl[128], shf[128], cvs[512];
    unsigned char* wtile = (unsigned char*)wtileq;
    int wgid = blockIdx.x;
    int b = wgid >> 9, pt = wgid & 511;
    int p0 = pt * 128;
    int t = threadIdx.x, l = t & 63, wv = t >> 6;
#pragma unroll
    for (int it = 0; it < 32; ++it) {
        int pid = it * 256 + t;  // 8192 pairs
        int o = pid >> 6, cp = (pid & 63) * 2;
        float2 f = *(const float2*)(final_w + (size_t)o * 640 + cp);
        unsigned int u = bfpair(f.x, f.y);
        int wa = (o * 256 + cp * 2) ^ ((o & 7) << 4);
        *(unsigned int*)(wtile + wa) = u;
    }
    if (t < 128) {
        scl[t] = ws[SCALEF_OFF + t];
        shf[t] = ws[SHIFTF_OFF + t];
    }
    int i3 = pt >> 6, jb = (pt & 1) * 4;
    for (int q = t; q < 512; q += 256) {
        int o = q >> 2, jj = q & 3;
        cvs[q] = ws[CONTRIB_OFF + (size_t)(b * 128 + o) * 64 + i3 * 8 + jb + jj];
    }
    __syncthreads();

    const float* xb = x + (size_t)b * C_ * P_;
    int pw = p0 + wv * 32;
    f32x4 acc[8][2];
#pragma unroll
    for (int i = 0; i < 8; ++i) {
        acc[i][0] = (f32x4){0.f, 0.f, 0.f, 0.f};
        acc[i][1] = (f32x4){0.f, 0.f, 0.f, 0.f};
    }
#pragma unroll
    for (int ks = 0; ks < 4; ++ks) {
        short8 bf[2];
#pragma unroll
        for (int nt = 0; nt < 2; ++nt) {
            const float* xp = xb + (size_t)(ks * 32 + (l >> 4) * 8) * P_ + (pw + nt * 16 + (l & 15));
            float f0 = xp[0 * P_], f1 = xp[1 * P_], f2 = xp[2 * P_], f3 = xp[3 * P_];
            float f4 = xp[4 * P_], f5 = xp[5 * P_], f6 = xp[6 * P_], f7 = xp[7 * P_];
            union { uint4 u; short8 s; } cvtu;
            cvtu.u = make_uint4(bfpair(f0, f1), bfpair(f2, f3), bfpair(f4, f5), bfpair(f6, f7));
            bf[nt] = cvtu.s;
        }
#pragma unroll
        for (int mt = 0; mt < 8; ++mt) {
            int ra = ((mt * 16 + (l & 15)) * 256 + ks * 64 + (l >> 4) * 16) ^ ((l & 7) << 4);
            short8 af = *(const short8*)(wtile + ra);
            acc[mt][0] = __builtin_amdgcn_mfma_f32_16x16x32_bf16(af, bf[0], acc[mt][0], 0, 0, 0);
            acc[mt][1] = __builtin_amdgcn_mfma_f32_16x16x32_bf16(af, bf[1], acc[mt][1], 0, 0, 0);
        }
    }
#pragma unroll
    for (int mt = 0; mt < 8; ++mt)
#pragma unroll
        for (int nt = 0; nt < 2; ++nt) {
            int p = pw + nt * 16 + (l & 15);
            int jj = ((p & 255) >> 5) & 3;
#pragma unroll
            for (int r = 0; r < 4; ++r) {
                int o = mt * 16 + (l >> 4) * 4 + r;
                float z = acc[mt][nt][r] + cvs[o * 4 + jj];
                out[(size_t)(b * 128 + o) * P_ + p] = fmaf(z, scl[o], shf[o]);
            }
        }
}

extern "C" void kernel_launch(void* const* d_in, const int* in_sizes, int n_in,
                              void* d_out, int out_size, void* d_ws, size_t ws_size,
                              hipStream_t stream) {
    const float* x = (const float*)d_in[0];
    const float* conv_w = (const float*)d_in[1];
    const float* conv_g = (const float*)d_in[2];
    const float* conv_b = (const float*)d_in[3];
    const float* final_w = (const float*)d_in[4];
    const float* final_g = (const float*)d_in[5];
    const float* final_b = (const float*)d_in[6];
    float* out = (float*)d_out;
    float* ws = (float*)d_ws;

    // single fused pass over x: fp32-exact block max/sum partials + bf16 Gram
    // (bf16 Gram partials live in d_out scratch until k_reduceG; k_out overwrites d_out)
    k_gram_pool<<<512, 512, 0, stream>>>(x, ws, (unsigned int*)d_out);
    k_reduceG<<<128, 256, 0, stream>>>((const unsigned int*)d_out, ws);
    k_reduceMS3<<<256, 128, 0, stream>>>(ws);
    k_pyramid<<<512, 64, 0, stream>>>(ws);
    k_conv_pool<<<64, 256, 0, stream>>>(conv_w, ws);
    k_bnstats_d<<<2, 256, 0, stream>>>(conv_g, conv_b, ws);
    k_contrib<<<B_ * 64, 128, 0, stream>>>(final_w, ws);
    k_stats<<<128, 128, 0, stream>>>(final_w, final_g, final_b, ws);
    k_out<<<2048, 256, 0, stream>>>(x, final_w, ws, out);
}